// Round 1
// baseline (207.033 us; speedup 1.0000x reference)
//
#include <hip/hip_runtime.h>
#include <hip/hip_bf16.h>
#include <cstdint>
#include <math.h>

#define S_LEN 2048
#define DM 1024
#define NQKV 1536
#define MROWS 4096   // B * S

typedef __attribute__((ext_vector_type(8))) short short8;
typedef __attribute__((ext_vector_type(4))) float f32x4;
typedef __attribute__((ext_vector_type(16))) float f32x16;

// 0.125 (1/sqrt(64)) * log2(e), folded into Q at RoPE time
#define QFOLD 0.18033688011112042f

__device__ __forceinline__ short f2bf(float x) {
  union { float f; uint32_t u; } v; v.f = x;
  uint32_t r = (v.u + 0x7fffu + ((v.u >> 16) & 1u)) >> 16;
  return (short)(uint16_t)r;
}

__device__ __forceinline__ uint32_t pk2(float a, float b) {
  __hip_bfloat162 h = __float22bfloat162_rn(make_float2(a, b));
  union { __hip_bfloat162 h2; uint32_t u; } cv; cv.h2 = h;
  return cv.u;
}

// ---------------- fp32 -> bf16 vectorized convert ----------------
__global__ void f32_to_bf16_vec(const float* __restrict__ in, short* __restrict__ out, int n4) {
  int i = blockIdx.x * blockDim.x + threadIdx.x;
  if (i < n4) {
    float4 v = ((const float4*)in)[i];
    short4 o;
    o.x = f2bf(v.x); o.y = f2bf(v.y); o.z = f2bf(v.z); o.w = f2bf(v.w);
    ((short4*)out)[i] = o;
  }
}

// ---------------- fp32 [R][C] -> bf16 transposed dst[c*R + r] ----------------
__global__ __launch_bounds__(256) void transpose_f32_bf16(const float* __restrict__ src,
    short* __restrict__ dst, int R, int C) {
  __shared__ short T[64 * 72];
  const int r0 = blockIdx.x * 64, c0 = blockIdx.y * 64;
  const int tid = threadIdx.x;
  #pragma unroll
  for (int i = 0; i < 4; ++i) {
    int chunk = tid + i * 256;
    int r = chunk >> 4, cc = (chunk & 15) * 4;
    float4 v = *(const float4*)&src[(size_t)(r0 + r) * C + c0 + cc];
    T[(cc + 0) * 72 + r] = f2bf(v.x);
    T[(cc + 1) * 72 + r] = f2bf(v.y);
    T[(cc + 2) * 72 + r] = f2bf(v.z);
    T[(cc + 3) * 72 + r] = f2bf(v.w);
  }
  __syncthreads();
  #pragma unroll
  for (int i = 0; i < 2; ++i) {
    int chunk = tid + i * 256;
    int rr = chunk >> 3, kk = (chunk & 7) * 8;
    *(uint4*)&dst[(size_t)(c0 + rr) * R + r0 + kk] = *(uint4*)&T[rr * 72 + kk];
  }
}

// ---------------- bf16 MFMA GEMM, m97-style global_load_lds staging ----------------
#define BM 128
#define BN 128
#define BKT 64

__global__ __launch_bounds__(256) void gemm_bf16(const short* __restrict__ A,
    const short* __restrict__ BT, float* __restrict__ C, int M, int N, int K) {
  __shared__ short As[BM * BKT];
  __shared__ short Bs[BN * BKT];
  const int tid = threadIdx.x;
  const int wave = tid >> 6, lane = tid & 63;
  const int quad = lane >> 4, l15 = lane & 15;
  const int wm = (wave >> 1) * 64, wn = (wave & 1) * 64;
  const int m0 = blockIdx.y * BM, n0 = blockIdx.x * BN;

  const int sr = wave * 32 + (lane >> 3);
  const int scol = (lane & 7) * 8;

  f32x4 acc[4][4] = {};

  for (int k0 = 0; k0 < K; k0 += BKT) {
    __syncthreads();
    #pragma unroll
    for (int j = 0; j < 4; ++j) {
      const int r = sr + j * 8;
      __builtin_amdgcn_global_load_lds(
          (const __attribute__((address_space(1))) void*)&A[(size_t)(m0 + r) * K + k0 + scol],
          (__attribute__((address_space(3))) void*)&As[(wave * 4 + j) * 512],
          16, 0, 0);
      __builtin_amdgcn_global_load_lds(
          (const __attribute__((address_space(1))) void*)&BT[(size_t)(n0 + r) * K + k0 + scol],
          (__attribute__((address_space(3))) void*)&Bs[(wave * 4 + j) * 512],
          16, 0, 0);
    }
    __syncthreads();
    #pragma unroll
    for (int ks = 0; ks < 2; ++ks) {
      short8 af[4], bfr[4];
      #pragma unroll
      for (int mi = 0; mi < 4; ++mi)
        af[mi] = *(const short8*)&As[(wm + mi*16 + l15)*BKT + ks*32 + quad*8];
      #pragma unroll
      for (int ni = 0; ni < 4; ++ni)
        bfr[ni] = *(const short8*)&Bs[(wn + ni*16 + l15)*BKT + ks*32 + quad*8];
      #pragma unroll
      for (int mi = 0; mi < 4; ++mi)
        #pragma unroll
        for (int ni = 0; ni < 4; ++ni)
          acc[mi][ni] = __builtin_amdgcn_mfma_f32_16x16x32_bf16(af[mi], bfr[ni], acc[mi][ni], 0, 0, 0);
    }
  }
  #pragma unroll
  for (int mi = 0; mi < 4; ++mi)
    #pragma unroll
    for (int ni = 0; ni < 4; ++ni)
      #pragma unroll
      for (int r = 0; r < 4; ++r)
        C[(size_t)(m0 + wm + mi*16 + quad*4 + r)*N + (n0 + wn + ni*16 + l15)] = acc[mi][ni][r];
}

// ---------------- RoPE + bf16 pack; Q gets scale*log2e folded in ----------------
// K rows are written XOR-SWIZZLED within each 64-short (128B) head segment:
// short index j -> j ^ ((s&7)<<3). This makes fattn7's ds_read_b128 of K
// conflict-free while keeping global_load_lds staging a linear copy.
__global__ void rope_kernel(const float* __restrict__ qkv, short* __restrict__ Qb,
                            short* __restrict__ Kb, short* __restrict__ Vb) {
  __shared__ float csn[64];
  const int row = blockIdx.x;
  const int s = row & (S_LEN - 1);
  const int tid = threadIdx.x;
  const float* rp = qkv + (size_t)row * NQKV;
  if (tid < 32) {
    float inv = exp2f(-(float)tid * 0.41524101186092029f);  // log2(10000)/32
    float ang = (float)s * inv;
    csn[tid] = cosf(ang);
    csn[tid + 32] = sinf(ang);
  }
  __syncthreads();
  #pragma unroll
  for (int i = 0; i < 2; ++i) {
    int p = tid + i * 256;
    int hh = p >> 5, j = p & 31;
    float cs = csn[j], sn = csn[j + 32];
    float x1 = rp[hh*64 + j], x2 = rp[hh*64 + j + 32];
    Qb[(size_t)row*1024 + hh*64 + j]      = f2bf((x1*cs - x2*sn) * QFOLD);
    Qb[(size_t)row*1024 + hh*64 + j + 32] = f2bf((x2*cs + x1*sn) * QFOLD);
  }
  if (tid < 128) {
    int hh = tid >> 5, j = tid & 31;
    float cs = csn[j], sn = csn[j + 32];
    float x1 = rp[1024 + hh*64 + j], x2 = rp[1024 + hh*64 + j + 32];
    const int sw = (s & 7) << 3;
    Kb[(size_t)row*256 + hh*64 + (j ^ sw)]        = f2bf(x1*cs - x2*sn);
    Kb[(size_t)row*256 + hh*64 + ((j + 32) ^ sw)] = f2bf(x2*cs + x1*sn);
  }
  Vb[(size_t)row*256 + tid] = f2bf(rp[1280 + tid]);
}

// ---------------- V transpose: Vb[b*S+s][kvh*64+d] -> Vt[(b*4+kvh)*64+d][s] ----------------
// Vt rows are written XOR-SWIZZLED within each 128-element kv block:
// s -> s ^ ((d&7)<<3), so fattn7's ds_read_b128 of V^T is conflict-free.
__global__ __launch_bounds__(256) void transpose_v(const short* __restrict__ Vb,
                                                   short* __restrict__ Vt) {
  __shared__ short T[64 * 72];
  const int s0 = blockIdx.x * 64;
  const int bh = blockIdx.y;
  const int b = bh >> 2, kvh = bh & 3;
  const int tid = threadIdx.x;
  #pragma unroll
  for (int i = 0; i < 2; ++i) {
    int chunk = tid + i * 256;
    int r = chunk >> 3, c = (chunk & 7) * 8;
    short8 v = *(const short8*)&Vb[(size_t)(b*S_LEN + s0 + r)*256 + kvh*64 + c];
    #pragma unroll
    for (int t = 0; t < 8; ++t) T[(c + t) * 72 + r] = v[t];
  }
  __syncthreads();
  #pragma unroll
  for (int i = 0; i < 2; ++i) {
    int chunk = tid + i * 256;
    int rr = chunk >> 3, kk = (chunk & 7) * 8;
    *(uint4*)&Vt[(size_t)(bh*64 + rr)*S_LEN + s0 + (kk ^ ((rr & 7) << 3))] = *(uint4*)&T[rr * 72 + kk];
  }
}

// ---------------- causal GQA flash attention v7: 32x32 MFMA, in-register P ----------------
// grid 512 = (b:2, h:16, pair:16). Block = 128 threads = 2 waves x 32 q-rows
// (64-q tile). Pairing jt/(31-jt) -> exactly 17 x 128-kv units per block.
// K and V^T staged via global_load_lds (linear copy; producers pre-swizzled),
// double-buffered LDS (64KB) -> 2 blocks/CU. QK^T swapped (mfma(K,Q)) so each
// lane holds P[:, q=lane&31]; PV A-frags built in-register with
// v_cvt_pk_bf16_f32 + v_permlane32_swap_b32 (no P LDS round-trip).
__global__ __launch_bounds__(128, 1) void fattn7(const short* __restrict__ Qb,
    const short* __restrict__ Kb, const short* __restrict__ Vt, short* __restrict__ Ctx) {
  __shared__ short Ks[2][128 * 64];    // [kv 128][d 64], content XOR-swizzled
  __shared__ short Vts[2][64 * 128];   // [d 64][kv 128], content XOR-swizzled
  const int idx = blockIdx.x;
  const int pi  = idx & 15;
  const int h   = (idx >> 4) & 15;
  const int b   = idx >> 8;
  const int kvh = h >> 2;
  const int tid = threadIdx.x, wav = tid >> 6, lane = tid & 63;
  const int l31 = lane & 31, hi = lane >> 5;
  const size_t qbase  = (size_t)b * S_LEN * 1024;
  const size_t kbase  = (size_t)b * S_LEN * 256;
  const size_t vtbase = (size_t)(b * 4 + kvh) * 64 * S_LEN;

  // per-thread staging source pointers (16B chunk each; linear copy, data
  // is pre-swizzled at the producer so LDS dest stays linear — rule #21)
  const short* kptr = Kb + kbase + (size_t)(wav * 8 + (lane >> 3)) * 256 + kvh * 64 + (lane & 7) * 8;
  const short* vptr = Vt + vtbase + (size_t)(wav * 4 + (lane >> 4)) * 2048 + (lane & 15) * 8;

#define STAGE(bi, k0s) do { \
    const short* kp_ = kptr + (size_t)(k0s) * 256; \
    const short* vp_ = vptr + (k0s); \
    short* kd_ = &Ks[bi][wav * 512]; \
    short* vd_ = &Vts[bi][wav * 512]; \
    _Pragma("unroll") \
    for (int i_ = 0; i_ < 8; ++i_) { \
      __builtin_amdgcn_global_load_lds((const __attribute__((address_space(1))) void*)(kp_ + i_ * 4096), \
          (__attribute__((address_space(3))) void*)(kd_ + i_ * 1024), 16, 0, 0); \
      __builtin_amdgcn_global_load_lds((const __attribute__((address_space(1))) void*)(vp_ + i_ * 16384), \
          (__attribute__((address_space(3))) void*)(vd_ + i_ * 1024), 16, 0, 0); \
    } \
  } while (0)

  for (int half = 0; half < 2; ++half) {
    const int jt = half ? (31 - pi) : pi;
    const int q0 = jt * 64;
    const int ntiles = (jt >> 1) + 1;     // ntiles(i)+ntiles(31-i) == 17
    const int qg = q0 + wav * 32 + l31;   // this lane's q column

    // Q B-frags: lane holds Q[q=l31][d = ks*16 + hi*8 + j]
    short8 qf[4];
    {
      const short* qp = &Qb[qbase + (size_t)qg * 1024 + h * 64 + hi * 8];
      #pragma unroll
      for (int ks = 0; ks < 4; ++ks) qf[ks] = *(const short8*)(qp + ks * 16);
    }

    f32x16 O0 = {}, O1 = {};
    float la0 = 0.f, la1 = 0.f, la2 = 0.f, la3 = 0.f;

    STAGE(0, 0);
    __syncthreads();

    for (int t = 0; t < ntiles; ++t) {
      const int cur = t & 1;
      const int k0 = t * 128;
      if (t + 1 < ntiles) STAGE((t + 1) & 1, (t + 1) * 128);

      const short* ks_ = Ks[cur];
      const short* vs_ = Vts[cur];

      // St = K Q^T : sc[kt] holds S[kv = k0+kt*32+crow(r,hi)][q = qg]
      f32x16 sc[4];
      #pragma unroll
      for (int kt = 0; kt < 4; ++kt) {
        const int r = kt * 32 + l31;
        const int rx = (r & 7) << 3;
        f32x16 a = {};
        #pragma unroll
        for (int ks2 = 0; ks2 < 4; ++ks2) {
          short8 kf = *(const short8*)&ks_[r * 64 + ((ks2 * 16 + hi * 8) ^ rx)];
          a = __builtin_amdgcn_mfma_f32_32x32x16_bf16(kf, qf[ks2], a, 0, 0, 0);
        }
        sc[kt] = a;
      }

      if (t == ntiles - 1) {
        #pragma unroll
        for (int kt = 0; kt < 4; ++kt)
          #pragma unroll
          for (int r = 0; r < 16; ++r) {
            const int kvg = k0 + kt * 32 + (r & 3) + 8 * (r >> 2) + 4 * hi;
            if (kvg > qg) sc[kt][r] = -1e30f;
          }
      }

      // no-max softmax: p = exp2(s); l accumulated per-lane (4-way trees).
      // Then build PV A-frags fully in-register (T12): cvt_pk pairs +
      // permlane32_swap. af[s] = P[q=l31][kv = s*16 + hi*8 + j].
      short8 af[8];
      #pragma unroll
      for (int kt = 0; kt < 4; ++kt) {
        #pragma unroll
        for (int r = 0; r < 16; ++r) sc[kt][r] = exp2f(sc[kt][r]);
        la0 += (sc[kt][0] + sc[kt][1]) + (sc[kt][2] + sc[kt][3]);
        la1 += (sc[kt][4] + sc[kt][5]) + (sc[kt][6] + sc[kt][7]);
        la2 += (sc[kt][8] + sc[kt][9]) + (sc[kt][10] + sc[kt][11]);
        la3 += (sc[kt][12] + sc[kt][13]) + (sc[kt][14] + sc[kt][15]);
        #pragma unroll
        for (int st = 0; st < 2; ++st) {
          uint32_t x0 = pk2(sc[kt][st * 8 + 0], sc[kt][st * 8 + 1]);
          uint32_t x1 = pk2(sc[kt][st * 8 + 2], sc[kt][st * 8 + 3]);
          uint32_t x2 = pk2(sc[kt][st * 8 + 4], sc[kt][st * 8 + 5]);
          uint32_t x3 = pk2(sc[kt][st * 8 + 6], sc[kt][st * 8 + 7]);
          // swap vdst.hi-lanes with vsrc.lo-lanes: x0 -> frag word0, x2 -> word2
          asm("v_permlane32_swap_b32 %0, %1" : "+v"(x0), "+v"(x2));
          asm("v_permlane32_swap_b32 %0, %1" : "+v"(x1), "+v"(x3));
          union { short8 s8; uint32_t u[4]; } cv;
          cv.u[0] = x0; cv.u[1] = x1; cv.u[2] = x2; cv.u[3] = x3;
          af[kt * 2 + st] = cv.s8;
        }
      }

      // O += P V : B-frag = V^T from LDS; lane holds V[kv = s*16+hi*8+j][d=l31(+32)]
      const int vx = (l31 & 7) << 3;
      #pragma unroll
      for (int s = 0; s < 8; ++s) {
        const int co = s * 16 + hi * 8;
        short8 bv0 = *(const short8*)&vs_[l31 * 128 + (co ^ vx)];
        O0 = __builtin_amdgcn_mfma_f32_32x32x16_bf16(af[s], bv0, O0, 0, 0, 0);
        short8 bv1 = *(const short8*)&vs_[(32 + l31) * 128 + (co ^ vx)];
        O1 = __builtin_amdgcn_mfma_f32_32x32x16_bf16(af[s], bv1, O1, 0, 0, 0);
      }

      __syncthreads();   // drains staged t+1 loads (vmcnt 0) + buffer handoff
    }

    // finalize: lane's l is partial over its kv subset for q=l31; other half
    // of kv lives at lane^32 (same l31)
    float ll = (la0 + la1) + (la2 + la3);
    ll += __shfl_xor(ll, 32, 64);
    const float inv = 1.0f / ll;
    #pragma unroll
    for (int r = 0; r < 16; ++r) {
      const int crow = (r & 3) + 8 * (r >> 2) + 4 * hi;
      const float invr = __shfl(inv, crow, 64);
      const size_t o = qbase + (size_t)(q0 + wav * 32 + crow) * 1024 + h * 64;
      Ctx[o + l31]      = f2bf(O0[r] * invr);
      Ctx[o + 32 + l31] = f2bf(O1[r] * invr);
    }
  }
#undef STAGE
}

extern "C" void kernel_launch(void* const* d_in, const int* in_sizes, int n_in,
                              void* d_out, int out_size, void* d_ws, size_t ws_size,
                              hipStream_t stream) {
  const float* x  = (const float*)d_in[0];
  const float* Wq = (const float*)d_in[1];
  const float* Wk = (const float*)d_in[2];
  const float* Wv = (const float*)d_in[3];
  const float* Wo = (const float*)d_in[4];
  float* out = (float*)d_out;

  char* w = (char*)d_ws;
  short* Xb    = (short*)w;  w += (size_t)MROWS * DM * 2;
  short* WcatT = (short*)w;  w += (size_t)NQKV * DM * 2;
  short* WoT   = (short*)w;  w += (size_t)DM * DM * 2;
  float* QKVf  = (float*)w;  w += (size_t)MROWS * NQKV * 4;
  short* Qbuf  = (short*)w;  w += (size_t)MROWS * DM * 2;
  short* Kbuf  = (short*)w;  w += (size_t)MROWS * 256 * 2;
  short* Vbuf  = (short*)w;  w += (size_t)MROWS * 256 * 2;
  short* Vt    = (short*)w;  w += (size_t)8 * 64 * S_LEN * 2;
  short* Ctx   = (short*)QKVf;   // QKVf dead after rope

  f32_to_bf16_vec<<<dim3(4096), dim3(256), 0, stream>>>(x, Xb, MROWS * DM / 4);
  transpose_f32_bf16<<<dim3(16, 16), dim3(256), 0, stream>>>(Wq, WcatT, 1024, 1024);
  transpose_f32_bf16<<<dim3(16, 4),  dim3(256), 0, stream>>>(Wk, WcatT + (size_t)1024*1024, 1024, 256);
  transpose_f32_bf16<<<dim3(16, 4),  dim3(256), 0, stream>>>(Wv, WcatT + (size_t)1280*1024, 1024, 256);
  transpose_f32_bf16<<<dim3(16, 16), dim3(256), 0, stream>>>(Wo, WoT, 1024, 1024);

  gemm_bf16<<<dim3(NQKV / BN, MROWS / BM), dim3(256), 0, stream>>>(Xb, WcatT, QKVf, MROWS, NQKV, DM);
  rope_kernel<<<dim3(MROWS), dim3(256), 0, stream>>>(QKVf, Qbuf, Kbuf, Vbuf);
  transpose_v<<<dim3(32, 8), dim3(256), 0, stream>>>(Vbuf, Vt);
  fattn7<<<dim3(512), dim3(128), 0, stream>>>(Qbuf, Kbuf, Vt, Ctx);
  gemm_bf16<<<dim3(DM / BN, MROWS / BM), dim3(256), 0, stream>>>(Ctx, WoT, out, MROWS, DM, DM);
}

// Round 2
// 191.751 us; speedup vs baseline: 1.0797x; 1.0797x over previous
//
#include <hip/hip_runtime.h>
#include <hip/hip_bf16.h>
#include <cstdint>
#include <math.h>

#define S_LEN 2048
#define DM 1024
#define NQKV 1536
#define MROWS 4096   // B * S

typedef __attribute__((ext_vector_type(8))) short short8;
typedef __attribute__((ext_vector_type(4))) float f32x4;
typedef __attribute__((ext_vector_type(16))) float f32x16;

// 0.125 (1/sqrt(64)) * log2(e), folded into Q at RoPE time
#define QFOLD 0.18033688011112042f

__device__ __forceinline__ short f2bf(float x) {
  union { float f; uint32_t u; } v; v.f = x;
  uint32_t r = (v.u + 0x7fffu + ((v.u >> 16) & 1u)) >> 16;
  return (short)(uint16_t)r;
}

__device__ __forceinline__ uint32_t pk2(float a, float b) {
  __hip_bfloat162 h = __float22bfloat162_rn(make_float2(a, b));
  union { __hip_bfloat162 h2; uint32_t u; } cv; cv.h2 = h;
  return cv.u;
}

// ---------------- fp32 -> bf16 vectorized convert ----------------
__global__ void f32_to_bf16_vec(const float* __restrict__ in, short* __restrict__ out, int n4) {
  int i = blockIdx.x * blockDim.x + threadIdx.x;
  if (i < n4) {
    float4 v = ((const float4*)in)[i];
    short4 o;
    o.x = f2bf(v.x); o.y = f2bf(v.y); o.z = f2bf(v.z); o.w = f2bf(v.w);
    ((short4*)out)[i] = o;
  }
}

// ---------------- fp32 [R][C] -> bf16 transposed dst[c*R + r] ----------------
__global__ __launch_bounds__(256) void transpose_f32_bf16(const float* __restrict__ src,
    short* __restrict__ dst, int R, int C) {
  __shared__ short T[64 * 72];
  const int r0 = blockIdx.x * 64, c0 = blockIdx.y * 64;
  const int tid = threadIdx.x;
  #pragma unroll
  for (int i = 0; i < 4; ++i) {
    int chunk = tid + i * 256;
    int r = chunk >> 4, cc = (chunk & 15) * 4;
    float4 v = *(const float4*)&src[(size_t)(r0 + r) * C + c0 + cc];
    T[(cc + 0) * 72 + r] = f2bf(v.x);
    T[(cc + 1) * 72 + r] = f2bf(v.y);
    T[(cc + 2) * 72 + r] = f2bf(v.z);
    T[(cc + 3) * 72 + r] = f2bf(v.w);
  }
  __syncthreads();
  #pragma unroll
  for (int i = 0; i < 2; ++i) {
    int chunk = tid + i * 256;
    int rr = chunk >> 3, kk = (chunk & 7) * 8;
    *(uint4*)&dst[(size_t)(c0 + rr) * R + r0 + kk] = *(uint4*)&T[rr * 72 + kk];
  }
}

// ---------------- bf16 MFMA GEMM, m97-style global_load_lds staging ----------------
#define BM 128
#define BN 128
#define BKT 64

__global__ __launch_bounds__(256) void gemm_bf16(const short* __restrict__ A,
    const short* __restrict__ BT, float* __restrict__ C, int M, int N, int K) {
  __shared__ short As[BM * BKT];
  __shared__ short Bs[BN * BKT];
  const int tid = threadIdx.x;
  const int wave = tid >> 6, lane = tid & 63;
  const int quad = lane >> 4, l15 = lane & 15;
  const int wm = (wave >> 1) * 64, wn = (wave & 1) * 64;
  const int m0 = blockIdx.y * BM, n0 = blockIdx.x * BN;

  const int sr = wave * 32 + (lane >> 3);
  const int scol = (lane & 7) * 8;

  f32x4 acc[4][4] = {};

  for (int k0 = 0; k0 < K; k0 += BKT) {
    __syncthreads();
    #pragma unroll
    for (int j = 0; j < 4; ++j) {
      const int r = sr + j * 8;
      __builtin_amdgcn_global_load_lds(
          (const __attribute__((address_space(1))) void*)&A[(size_t)(m0 + r) * K + k0 + scol],
          (__attribute__((address_space(3))) void*)&As[(wave * 4 + j) * 512],
          16, 0, 0);
      __builtin_amdgcn_global_load_lds(
          (const __attribute__((address_space(1))) void*)&BT[(size_t)(n0 + r) * K + k0 + scol],
          (__attribute__((address_space(3))) void*)&Bs[(wave * 4 + j) * 512],
          16, 0, 0);
    }
    __syncthreads();
    #pragma unroll
    for (int ks = 0; ks < 2; ++ks) {
      short8 af[4], bfr[4];
      #pragma unroll
      for (int mi = 0; mi < 4; ++mi)
        af[mi] = *(const short8*)&As[(wm + mi*16 + l15)*BKT + ks*32 + quad*8];
      #pragma unroll
      for (int ni = 0; ni < 4; ++ni)
        bfr[ni] = *(const short8*)&Bs[(wn + ni*16 + l15)*BKT + ks*32 + quad*8];
      #pragma unroll
      for (int mi = 0; mi < 4; ++mi)
        #pragma unroll
        for (int ni = 0; ni < 4; ++ni)
          acc[mi][ni] = __builtin_amdgcn_mfma_f32_16x16x32_bf16(af[mi], bfr[ni], acc[mi][ni], 0, 0, 0);
    }
  }
  #pragma unroll
  for (int mi = 0; mi < 4; ++mi)
    #pragma unroll
    for (int ni = 0; ni < 4; ++ni)
      #pragma unroll
      for (int r = 0; r < 4; ++r)
        C[(size_t)(m0 + wm + mi*16 + quad*4 + r)*N + (n0 + wn + ni*16 + l15)] = acc[mi][ni][r];
}

// ---------------- RoPE + bf16 pack; Q gets scale*log2e folded in ----------------
// K rows are written XOR-SWIZZLED within each 64-short (128B) head segment:
// short index j -> j ^ ((s&7)<<3). This makes fattn8's ds_read_b128 of K
// conflict-free while keeping global_load_lds staging a linear copy.
__global__ void rope_kernel(const float* __restrict__ qkv, short* __restrict__ Qb,
                            short* __restrict__ Kb, short* __restrict__ Vb) {
  __shared__ float csn[64];
  const int row = blockIdx.x;
  const int s = row & (S_LEN - 1);
  const int tid = threadIdx.x;
  const float* rp = qkv + (size_t)row * NQKV;
  if (tid < 32) {
    float inv = exp2f(-(float)tid * 0.41524101186092029f);  // log2(10000)/32
    float ang = (float)s * inv;
    csn[tid] = cosf(ang);
    csn[tid + 32] = sinf(ang);
  }
  __syncthreads();
  #pragma unroll
  for (int i = 0; i < 2; ++i) {
    int p = tid + i * 256;
    int hh = p >> 5, j = p & 31;
    float cs = csn[j], sn = csn[j + 32];
    float x1 = rp[hh*64 + j], x2 = rp[hh*64 + j + 32];
    Qb[(size_t)row*1024 + hh*64 + j]      = f2bf((x1*cs - x2*sn) * QFOLD);
    Qb[(size_t)row*1024 + hh*64 + j + 32] = f2bf((x2*cs + x1*sn) * QFOLD);
  }
  if (tid < 128) {
    int hh = tid >> 5, j = tid & 31;
    float cs = csn[j], sn = csn[j + 32];
    float x1 = rp[1024 + hh*64 + j], x2 = rp[1024 + hh*64 + j + 32];
    const int sw = (s & 7) << 3;
    Kb[(size_t)row*256 + hh*64 + (j ^ sw)]        = f2bf(x1*cs - x2*sn);
    Kb[(size_t)row*256 + hh*64 + ((j + 32) ^ sw)] = f2bf(x2*cs + x1*sn);
  }
  Vb[(size_t)row*256 + tid] = f2bf(rp[1280 + tid]);
}

// ---------------- V transpose: Vb[b*S+s][kvh*64+d] -> Vt[(b*4+kvh)*64+d][s] ----------------
// Vt rows are written XOR-SWIZZLED within each 128-element kv block:
// s -> s ^ ((d&7)<<3), so fattn8's ds_read_b128 of V^T is conflict-free.
__global__ __launch_bounds__(256) void transpose_v(const short* __restrict__ Vb,
                                                   short* __restrict__ Vt) {
  __shared__ short T[64 * 72];
  const int s0 = blockIdx.x * 64;
  const int bh = blockIdx.y;
  const int b = bh >> 2, kvh = bh & 3;
  const int tid = threadIdx.x;
  #pragma unroll
  for (int i = 0; i < 2; ++i) {
    int chunk = tid + i * 256;
    int r = chunk >> 3, c = (chunk & 7) * 8;
    short8 v = *(const short8*)&Vb[(size_t)(b*S_LEN + s0 + r)*256 + kvh*64 + c];
    #pragma unroll
    for (int t = 0; t < 8; ++t) T[(c + t) * 72 + r] = v[t];
  }
  __syncthreads();
  #pragma unroll
  for (int i = 0; i < 2; ++i) {
    int chunk = tid + i * 256;
    int rr = chunk >> 3, kk = (chunk & 7) * 8;
    *(uint4*)&Vt[(size_t)(bh*64 + rr)*S_LEN + s0 + (kk ^ ((rr & 7) << 3))] = *(uint4*)&T[rr * 72 + kk];
  }
}

// ---------------- causal GQA flash attention v8: kv-split across wave pairs ----------------
// grid 512 = (b:2, h:16, pair:16). Block = 256 threads = 4 waves:
//   qs = wave&1  -> q-subtile of 32 (64-q tile per half)
//   g  = wave>>1 -> kv half (0-63 / 64-127) of each staged 128-kv unit
// All 4 waves share staged K/V tiles, uniform loop count (no divergent
// barriers). No-max softmax => partial O/l over disjoint kv combine
// LINEARLY: group 0 spills O,l to LDS scratch, group 1 adds + normalizes +
// writes Ctx. LDS 64KB double-buffered -> 2 blocks/CU = 8 waves/CU (2/SIMD);
// co-resident blocks desync and hide each other's barrier/vmcnt drains.
__global__ __launch_bounds__(256, 2) void fattn8(const short* __restrict__ Qb,
    const short* __restrict__ Kb, const short* __restrict__ Vt, short* __restrict__ Ctx) {
  __shared__ short SMEM[32768];   // 64KB: Ks[2][128*64] @ 0, Vts[2][64*128] @ 16384
  const int idx = blockIdx.x;
  const int pi  = idx & 15;
  const int h   = (idx >> 4) & 15;
  const int b   = idx >> 8;
  const int kvh = h >> 2;
  const int tid = threadIdx.x, wav = tid >> 6, lane = tid & 63;
  const int l31 = lane & 31, hi = lane >> 5;
  const int qs = wav & 1, g = wav >> 1;
  const int sx = (l31 & 7) << 3;           // XOR-swizzle key (matches producers)
  const size_t qbase  = (size_t)b * S_LEN * 1024;
  const size_t kbase  = (size_t)b * S_LEN * 256;
  const size_t vtbase = (size_t)(b * 4 + kvh) * 64 * S_LEN;

  // staging source pointers (16B chunk/lane; linear LDS dest, data pre-swizzled
  // at producers — rule #21). Wave w stages K rows [w*32,w*32+32), V d-rows [w*16,+16).
  const short* kptr = Kb + kbase + (size_t)(wav * 32 + (lane >> 3)) * 256 + kvh * 64 + (lane & 7) * 8;
  const short* vptr = Vt + vtbase + (size_t)(wav * 16 + (lane >> 4)) * 2048 + (lane & 15) * 8;

#define STAGE(bi, k0s) do { \
    const short* kp_ = kptr + (size_t)(k0s) * 256; \
    const short* vp_ = vptr + (k0s); \
    short* kd_ = &SMEM[(bi) * 8192 + wav * 2048]; \
    short* vd_ = &SMEM[16384 + (bi) * 8192 + wav * 2048]; \
    _Pragma("unroll") \
    for (int i_ = 0; i_ < 4; ++i_) { \
      __builtin_amdgcn_global_load_lds((const __attribute__((address_space(1))) void*)(kp_ + i_ * 2048), \
          (__attribute__((address_space(3))) void*)(kd_ + i_ * 512), 16, 0, 0); \
      __builtin_amdgcn_global_load_lds((const __attribute__((address_space(1))) void*)(vp_ + i_ * 8192), \
          (__attribute__((address_space(3))) void*)(vd_ + i_ * 512), 16, 0, 0); \
    } \
  } while (0)

  for (int half = 0; half < 2; ++half) {
    const int jt = half ? (31 - pi) : pi;
    const int q0 = jt * 64;
    const int ntiles = (jt >> 1) + 1;     // 128-kv units; ntiles(i)+ntiles(31-i) == 17
    const int qg = q0 + qs * 32 + l31;    // this lane's q column

    // Q B-frags: lane holds Q[q=l31 of subtile][d = ks*16 + hi*8 + j]
    short8 qf[4];
    {
      const short* qp = &Qb[qbase + (size_t)qg * 1024 + h * 64 + hi * 8];
      #pragma unroll
      for (int ks = 0; ks < 4; ++ks) qf[ks] = *(const short8*)(qp + ks * 16);
    }

    f32x16 O0 = {}, O1 = {};
    float la0 = 0.f, la1 = 0.f, la2 = 0.f, la3 = 0.f;

    STAGE(0, 0);
    __syncthreads();

    for (int t = 0; t < ntiles; ++t) {
      const int cur = t & 1;
      const int k0 = t * 128;
      if (t + 1 < ntiles) STAGE((t + 1) & 1, (t + 1) * 128);

      const short* ks_ = &SMEM[cur * 8192];
      const short* vs_ = &SMEM[16384 + cur * 8192];

      // St = K Q^T over this wave's 64-kv half: sc[kt][r] = S[kv=k0+g*64+kt*32+crow(r,hi)][q=qg]
      f32x16 sc[2];
      __builtin_amdgcn_s_setprio(1);
      #pragma unroll
      for (int kt = 0; kt < 2; ++kt) {
        const int r = g * 64 + kt * 32 + l31;
        f32x16 a = {};
        #pragma unroll
        for (int ks2 = 0; ks2 < 4; ++ks2) {
          short8 kf = *(const short8*)&ks_[r * 64 + ((ks2 * 16 + hi * 8) ^ sx)];
          a = __builtin_amdgcn_mfma_f32_32x32x16_bf16(kf, qf[ks2], a, 0, 0, 0);
        }
        sc[kt] = a;
      }
      __builtin_amdgcn_s_setprio(0);

      if (t == ntiles - 1) {
        #pragma unroll
        for (int kt = 0; kt < 2; ++kt)
          #pragma unroll
          for (int r = 0; r < 16; ++r) {
            const int kvg = k0 + g * 64 + kt * 32 + (r & 3) + 8 * (r >> 2) + 4 * hi;
            if (kvg > qg) sc[kt][r] = -1e30f;
          }
      }

      // no-max softmax: p = exp2(s); build PV A-frags in-register (T12):
      // af[s] = P[q=l31][kv_local = s*16 + hi*8 + j]  (kv_local within the 64-half)
      short8 af[4];
      #pragma unroll
      for (int kt = 0; kt < 2; ++kt) {
        #pragma unroll
        for (int r = 0; r < 16; ++r) sc[kt][r] = exp2f(sc[kt][r]);
        la0 += (sc[kt][0] + sc[kt][1]) + (sc[kt][2] + sc[kt][3]);
        la1 += (sc[kt][4] + sc[kt][5]) + (sc[kt][6] + sc[kt][7]);
        la2 += (sc[kt][8] + sc[kt][9]) + (sc[kt][10] + sc[kt][11]);
        la3 += (sc[kt][12] + sc[kt][13]) + (sc[kt][14] + sc[kt][15]);
        #pragma unroll
        for (int st = 0; st < 2; ++st) {
          uint32_t x0 = pk2(sc[kt][st * 8 + 0], sc[kt][st * 8 + 1]);
          uint32_t x1 = pk2(sc[kt][st * 8 + 2], sc[kt][st * 8 + 3]);
          uint32_t x2 = pk2(sc[kt][st * 8 + 4], sc[kt][st * 8 + 5]);
          uint32_t x3 = pk2(sc[kt][st * 8 + 6], sc[kt][st * 8 + 7]);
          asm("v_permlane32_swap_b32 %0, %1" : "+v"(x0), "+v"(x2));
          asm("v_permlane32_swap_b32 %0, %1" : "+v"(x1), "+v"(x3));
          union { short8 s8; uint32_t u[4]; } cv;
          cv.u[0] = x0; cv.u[1] = x1; cv.u[2] = x2; cv.u[3] = x3;
          af[kt * 2 + st] = cv.s8;
        }
      }

      // O += P V over the 64-kv half: B-frag from V^T LDS rows d=l31 / d=32+l31
      __builtin_amdgcn_s_setprio(1);
      #pragma unroll
      for (int s = 0; s < 4; ++s) {
        const int co = g * 64 + s * 16 + hi * 8;
        short8 bv0 = *(const short8*)&vs_[l31 * 128 + (co ^ sx)];
        O0 = __builtin_amdgcn_mfma_f32_32x32x16_bf16(af[s], bv0, O0, 0, 0, 0);
        short8 bv1 = *(const short8*)&vs_[(32 + l31) * 128 + (co ^ sx)];
        O1 = __builtin_amdgcn_mfma_f32_32x32x16_bf16(af[s], bv1, O1, 0, 0, 0);
      }
      __builtin_amdgcn_s_setprio(0);

      __syncthreads();   // drains staged t+1 loads + buffer handoff
    }

    // ---- combine the two kv halves (linear: no-max softmax has no rescale) ----
    float ll = (la0 + la1) + (la2 + la3);
    ll += __shfl_xor(ll, 32, 64);     // lane now holds l for q=l31 over its 64-kv half

    float* Os = (float*)SMEM;                 // [2 qs][64 lane][33] padded
    float* Ls = (float*)SMEM + 2 * 64 * 33;   // [2 qs][64 lane]
    if (g == 0) {
      float* op = &Os[(qs * 64 + lane) * 33];
      #pragma unroll
      for (int r = 0; r < 16; ++r) { op[r] = O0[r]; op[16 + r] = O1[r]; }
      Ls[qs * 64 + lane] = ll;
    }
    __syncthreads();
    if (g == 1) {
      const float lt = ll + Ls[qs * 64 + lane];
      const float inv = 1.0f / lt;
      const float* op = &Os[(qs * 64 + lane) * 33];
      #pragma unroll
      for (int r = 0; r < 16; ++r) { O0[r] += op[r]; O1[r] += op[16 + r]; }
      #pragma unroll
      for (int r = 0; r < 16; ++r) {
        const int crow = (r & 3) + 8 * (r >> 2) + 4 * hi;
        const float invr = __shfl(inv, crow, 64);
        const size_t o = qbase + (size_t)(q0 + qs * 32 + crow) * 1024 + h * 64;
        Ctx[o + l31]      = f2bf(O0[r] * invr);
        Ctx[o + 32 + l31] = f2bf(O1[r] * invr);
      }
    }
    __syncthreads();   // scratch dead before next half's STAGE overwrites it
  }
#undef STAGE
}

extern "C" void kernel_launch(void* const* d_in, const int* in_sizes, int n_in,
                              void* d_out, int out_size, void* d_ws, size_t ws_size,
                              hipStream_t stream) {
  const float* x  = (const float*)d_in[0];
  const float* Wq = (const float*)d_in[1];
  const float* Wk = (const float*)d_in[2];
  const float* Wv = (const float*)d_in[3];
  const float* Wo = (const float*)d_in[4];
  float* out = (float*)d_out;

  char* w = (char*)d_ws;
  short* Xb    = (short*)w;  w += (size_t)MROWS * DM * 2;
  short* WcatT = (short*)w;  w += (size_t)NQKV * DM * 2;
  short* WoT   = (short*)w;  w += (size_t)DM * DM * 2;
  float* QKVf  = (float*)w;  w += (size_t)MROWS * NQKV * 4;
  short* Qbuf  = (short*)w;  w += (size_t)MROWS * DM * 2;
  short* Kbuf  = (short*)w;  w += (size_t)MROWS * 256 * 2;
  short* Vbuf  = (short*)w;  w += (size_t)MROWS * 256 * 2;
  short* Vt    = (short*)w;  w += (size_t)8 * 64 * S_LEN * 2;
  short* Ctx   = (short*)QKVf;   // QKVf dead after rope

  f32_to_bf16_vec<<<dim3(4096), dim3(256), 0, stream>>>(x, Xb, MROWS * DM / 4);
  transpose_f32_bf16<<<dim3(16, 16), dim3(256), 0, stream>>>(Wq, WcatT, 1024, 1024);
  transpose_f32_bf16<<<dim3(16, 4),  dim3(256), 0, stream>>>(Wk, WcatT + (size_t)1024*1024, 1024, 256);
  transpose_f32_bf16<<<dim3(16, 4),  dim3(256), 0, stream>>>(Wv, WcatT + (size_t)1280*1024, 1024, 256);
  transpose_f32_bf16<<<dim3(16, 16), dim3(256), 0, stream>>>(Wo, WoT, 1024, 1024);

  gemm_bf16<<<dim3(NQKV / BN, MROWS / BM), dim3(256), 0, stream>>>(Xb, WcatT, QKVf, MROWS, NQKV, DM);
  rope_kernel<<<dim3(MROWS), dim3(256), 0, stream>>>(QKVf, Qbuf, Kbuf, Vbuf);
  transpose_v<<<dim3(32, 8), dim3(256), 0, stream>>>(Vbuf, Vt);
  fattn8<<<dim3(512), dim3(256), 0, stream>>>(Qbuf, Kbuf, Vt, Ctx);
  gemm_bf16<<<dim3(DM / BN, MROWS / BM), dim3(256), 0, stream>>>(Ctx, WoT, out, MROWS, DM, DM);
}

// Round 3
// 185.252 us; speedup vs baseline: 1.1176x; 1.0351x over previous
//
#include <hip/hip_runtime.h>
#include <hip/hip_bf16.h>
#include <cstdint>
#include <math.h>

#define S_LEN 2048
#define DM 1024
#define NQKV 1536
#define MROWS 4096   // B * S
#define BKT 64

typedef __attribute__((ext_vector_type(8))) short short8;
typedef __attribute__((ext_vector_type(4))) float f32x4;
typedef __attribute__((ext_vector_type(16))) float f32x16;

// 0.125 (1/sqrt(64)) * log2(e), folded into Q at RoPE time
#define QFOLD 0.18033688011112042f

__device__ __forceinline__ short f2bf(float x) {
  union { float f; uint32_t u; } v; v.f = x;
  uint32_t r = (v.u + 0x7fffu + ((v.u >> 16) & 1u)) >> 16;
  return (short)(uint16_t)r;
}

__device__ __forceinline__ uint32_t pk2(float a, float b) {
  __hip_bfloat162 h = __float22bfloat162_rn(make_float2(a, b));
  union { __hip_bfloat162 h2; uint32_t u; } cv; cv.h2 = h;
  return cv.u;
}

// ---------------- fp32 -> bf16 vectorized convert ----------------
__global__ void f32_to_bf16_vec(const float* __restrict__ in, short* __restrict__ out, int n4) {
  int i = blockIdx.x * blockDim.x + threadIdx.x;
  if (i < n4) {
    float4 v = ((const float4*)in)[i];
    short4 o;
    o.x = f2bf(v.x); o.y = f2bf(v.y); o.z = f2bf(v.z); o.w = f2bf(v.w);
    ((short4*)out)[i] = o;
  }
}

// ---------------- fp32 [R][C] -> bf16 transposed dst[c*R + r] ----------------
__global__ __launch_bounds__(256) void transpose_f32_bf16(const float* __restrict__ src,
    short* __restrict__ dst, int R, int C) {
  __shared__ short T[64 * 72];
  const int r0 = blockIdx.x * 64, c0 = blockIdx.y * 64;
  const int tid = threadIdx.x;
  #pragma unroll
  for (int i = 0; i < 4; ++i) {
    int chunk = tid + i * 256;
    int r = chunk >> 4, cc = (chunk & 15) * 4;
    float4 v = *(const float4*)&src[(size_t)(r0 + r) * C + c0 + cc];
    T[(cc + 0) * 72 + r] = f2bf(v.x);
    T[(cc + 1) * 72 + r] = f2bf(v.y);
    T[(cc + 2) * 72 + r] = f2bf(v.z);
    T[(cc + 3) * 72 + r] = f2bf(v.w);
  }
  __syncthreads();
  #pragma unroll
  for (int i = 0; i < 2; ++i) {
    int chunk = tid + i * 256;
    int rr = chunk >> 3, kk = (chunk & 7) * 8;
    *(uint4*)&dst[(size_t)(c0 + rr) * R + r0 + kk] = *(uint4*)&T[rr * 72 + kk];
  }
}

// ---------------- bf16 MFMA GEMM, m97-style staging, tile-templated ----------------
// BMT x BNT tile, 4 waves in 2x2 layout, BKT=64 K-step, global_load_lds width-16.
// 64x128 gives 2-4 co-resident blocks/CU for the narrow-N GEMMs in this problem.
template<int BMT, int BNT>
__global__ __launch_bounds__(256) void gemm_bf16_t(const short* __restrict__ A,
    const short* __restrict__ BT, float* __restrict__ C, int M, int N, int K) {
  constexpr int MI = BMT / 32, NI = BNT / 32;
  __shared__ short As[BMT * BKT];
  __shared__ short Bs[BNT * BKT];
  const int tid = threadIdx.x;
  const int wave = tid >> 6, lane = tid & 63;
  const int quad = lane >> 4, l15 = lane & 15;
  const int wm = (wave >> 1) * (BMT / 2), wn = (wave & 1) * (BNT / 2);
  const int m0 = blockIdx.y * BMT, n0 = blockIdx.x * BNT;
  const int rA = wave * (BMT / 4) + (lane >> 3);
  const int rB = wave * (BNT / 4) + (lane >> 3);
  const int scol = (lane & 7) * 8;

  f32x4 acc[MI][NI] = {};

  for (int k0 = 0; k0 < K; k0 += BKT) {
    __syncthreads();
    #pragma unroll
    for (int j = 0; j < MI; ++j)
      __builtin_amdgcn_global_load_lds(
          (const __attribute__((address_space(1))) void*)&A[(size_t)(m0 + rA + j * 8) * K + k0 + scol],
          (__attribute__((address_space(3))) void*)&As[(wave * MI + j) * 512],
          16, 0, 0);
    #pragma unroll
    for (int j = 0; j < NI; ++j)
      __builtin_amdgcn_global_load_lds(
          (const __attribute__((address_space(1))) void*)&BT[(size_t)(n0 + rB + j * 8) * K + k0 + scol],
          (__attribute__((address_space(3))) void*)&Bs[(wave * NI + j) * 512],
          16, 0, 0);
    __syncthreads();
    #pragma unroll
    for (int ks = 0; ks < 2; ++ks) {
      short8 af[MI], bfr[NI];
      #pragma unroll
      for (int mi = 0; mi < MI; ++mi)
        af[mi] = *(const short8*)&As[(wm + mi*16 + l15)*BKT + ks*32 + quad*8];
      #pragma unroll
      for (int ni = 0; ni < NI; ++ni)
        bfr[ni] = *(const short8*)&Bs[(wn + ni*16 + l15)*BKT + ks*32 + quad*8];
      #pragma unroll
      for (int mi = 0; mi < MI; ++mi)
        #pragma unroll
        for (int ni = 0; ni < NI; ++ni)
          acc[mi][ni] = __builtin_amdgcn_mfma_f32_16x16x32_bf16(af[mi], bfr[ni], acc[mi][ni], 0, 0, 0);
    }
  }
  #pragma unroll
  for (int mi = 0; mi < MI; ++mi)
    #pragma unroll
    for (int ni = 0; ni < NI; ++ni)
      #pragma unroll
      for (int r = 0; r < 4; ++r)
        C[(size_t)(m0 + wm + mi*16 + quad*4 + r)*N + (n0 + wn + ni*16 + l15)] = acc[mi][ni][r];
}

// ---------------- RoPE + bf16 pack; Q gets scale*log2e folded in ----------------
// K rows are written XOR-SWIZZLED within each 64-short (128B) head segment:
// short index j -> j ^ ((s&7)<<3). This makes fattn's ds_read_b128 of K
// conflict-free while keeping global_load_lds staging a linear copy.
__global__ void rope_kernel(const float* __restrict__ qkv, short* __restrict__ Qb,
                            short* __restrict__ Kb, short* __restrict__ Vb) {
  __shared__ float csn[64];
  const int row = blockIdx.x;
  const int s = row & (S_LEN - 1);
  const int tid = threadIdx.x;
  const float* rp = qkv + (size_t)row * NQKV;
  if (tid < 32) {
    float inv = exp2f(-(float)tid * 0.41524101186092029f);  // log2(10000)/32
    float ang = (float)s * inv;
    csn[tid] = cosf(ang);
    csn[tid + 32] = sinf(ang);
  }
  __syncthreads();
  #pragma unroll
  for (int i = 0; i < 2; ++i) {
    int p = tid + i * 256;
    int hh = p >> 5, j = p & 31;
    float cs = csn[j], sn = csn[j + 32];
    float x1 = rp[hh*64 + j], x2 = rp[hh*64 + j + 32];
    Qb[(size_t)row*1024 + hh*64 + j]      = f2bf((x1*cs - x2*sn) * QFOLD);
    Qb[(size_t)row*1024 + hh*64 + j + 32] = f2bf((x2*cs + x1*sn) * QFOLD);
  }
  if (tid < 128) {
    int hh = tid >> 5, j = tid & 31;
    float cs = csn[j], sn = csn[j + 32];
    float x1 = rp[1024 + hh*64 + j], x2 = rp[1024 + hh*64 + j + 32];
    const int sw = (s & 7) << 3;
    Kb[(size_t)row*256 + hh*64 + (j ^ sw)]        = f2bf(x1*cs - x2*sn);
    Kb[(size_t)row*256 + hh*64 + ((j + 32) ^ sw)] = f2bf(x2*cs + x1*sn);
  }
  Vb[(size_t)row*256 + tid] = f2bf(rp[1280 + tid]);
}

// ---------------- V transpose: Vb[b*S+s][kvh*64+d] -> Vt[(b*4+kvh)*64+d][s] ----------------
// Vt rows are written XOR-SWIZZLED within each 128-element kv block:
// s -> s ^ ((d&7)<<3), so fattn's ds_read_b128 of V^T is conflict-free.
__global__ __launch_bounds__(256) void transpose_v(const short* __restrict__ Vb,
                                                   short* __restrict__ Vt) {
  __shared__ short T[64 * 72];
  const int s0 = blockIdx.x * 64;
  const int bh = blockIdx.y;
  const int b = bh >> 2, kvh = bh & 3;
  const int tid = threadIdx.x;
  #pragma unroll
  for (int i = 0; i < 2; ++i) {
    int chunk = tid + i * 256;
    int r = chunk >> 3, c = (chunk & 7) * 8;
    short8 v = *(const short8*)&Vb[(size_t)(b*S_LEN + s0 + r)*256 + kvh*64 + c];
    #pragma unroll
    for (int t = 0; t < 8; ++t) T[(c + t) * 72 + r] = v[t];
  }
  __syncthreads();
  #pragma unroll
  for (int i = 0; i < 2; ++i) {
    int chunk = tid + i * 256;
    int rr = chunk >> 3, kk = (chunk & 7) * 8;
    *(uint4*)&Vt[(size_t)(bh*64 + rr)*S_LEN + s0 + (kk ^ ((rr & 7) << 3))] = *(uint4*)&T[rr * 72 + kk];
  }
}

// ---------------- causal GQA flash attention v9: 8 waves, 4-way kv split ----------------
// grid 512 = (b:2, h:16, pair:16). Block = 512 threads = 8 waves:
//   qs = wav&1  -> q-subtile of 32 (64-q tile per half)
//   g  = wav>>1 -> kv quarter (32 rows) of each staged 128-kv unit
// Pairing jt/(31-jt) -> uniform 17 x 128-kv units per block. K/V staged via
// global_load_lds (linear; producers pre-swizzled), double-buffered 64KB LDS
// -> 2 blocks/CU = 16 waves/CU (4/SIMD). No-max softmax: partial O/l over
// disjoint kv combine LINEARLY via 3-spill + reduce in LDS once per half.
__global__ __launch_bounds__(512, 4) void fattn9(const short* __restrict__ Qb,
    const short* __restrict__ Kb, const short* __restrict__ Vt, short* __restrict__ Ctx) {
  __shared__ short SMEM[32768];   // 64KB: Ks[2][128*64] @ 0, Vts[2][64*128] @ 16384
  const int idx = blockIdx.x;
  const int pi  = idx & 15;
  const int h   = (idx >> 4) & 15;
  const int b   = idx >> 8;
  const int kvh = h >> 2;
  const int tid = threadIdx.x, wav = tid >> 6, lane = tid & 63;
  const int l31 = lane & 31, hi = lane >> 5;
  const int qs = wav & 1, g = wav >> 1;    // g in 0..3
  const int sx = (l31 & 7) << 3;           // XOR-swizzle key (matches producers)
  const size_t qbase  = (size_t)b * S_LEN * 1024;
  const size_t kbase  = (size_t)b * S_LEN * 256;
  const size_t vtbase = (size_t)(b * 4 + kvh) * 64 * S_LEN;

  // staging (8 waves): wave stages K rows [wav*16,+16), V d-rows [wav*8,+8);
  // 2+2 width-16 global_load_lds per wave per unit; linear LDS dest (rule #21).
  const short* kptr = Kb + kbase + (size_t)(wav * 16 + (lane >> 3)) * 256 + kvh * 64 + (lane & 7) * 8;
  const short* vptr = Vt + vtbase + (size_t)(wav * 8 + (lane >> 4)) * 2048 + (lane & 15) * 8;

#define STAGE(bi, k0s) do { \
    const short* kp_ = kptr + (size_t)(k0s) * 256; \
    const short* vp_ = vptr + (k0s); \
    short* kd_ = &SMEM[(bi) * 8192 + wav * 1024]; \
    short* vd_ = &SMEM[16384 + (bi) * 8192 + wav * 1024]; \
    _Pragma("unroll") \
    for (int i_ = 0; i_ < 2; ++i_) { \
      __builtin_amdgcn_global_load_lds((const __attribute__((address_space(1))) void*)(kp_ + i_ * 2048), \
          (__attribute__((address_space(3))) void*)(kd_ + i_ * 512), 16, 0, 0); \
      __builtin_amdgcn_global_load_lds((const __attribute__((address_space(1))) void*)(vp_ + i_ * 8192), \
          (__attribute__((address_space(3))) void*)(vd_ + i_ * 512), 16, 0, 0); \
    } \
  } while (0)

  for (int half = 0; half < 2; ++half) {
    const int jt = half ? (31 - pi) : pi;
    const int q0 = jt * 64;
    const int ntiles = (jt >> 1) + 1;     // 128-kv units; ntiles(i)+ntiles(31-i) == 17
    const int qg = q0 + qs * 32 + l31;    // this lane's q column

    // Q B-frags: lane holds Q[q=l31 of subtile][d = ks*16 + hi*8 + j]
    short8 qf[4];
    {
      const short* qp = &Qb[qbase + (size_t)qg * 1024 + h * 64 + hi * 8];
      #pragma unroll
      for (int ks = 0; ks < 4; ++ks) qf[ks] = *(const short8*)(qp + ks * 16);
    }

    f32x16 O0 = {}, O1 = {};
    float la0 = 0.f, la1 = 0.f, la2 = 0.f, la3 = 0.f;

    STAGE(0, 0);
    __syncthreads();

    for (int t = 0; t < ntiles; ++t) {
      const int cur = t & 1;
      const int k0 = t * 128;
      if (t + 1 < ntiles) STAGE((t + 1) & 1, (t + 1) * 128);

      const short* ks_ = &SMEM[cur * 8192];
      const short* vs_ = &SMEM[16384 + cur * 8192];

      // St = K Q^T over this wave's 32-kv quarter:
      // sc[r] = S[kv = k0 + g*32 + crow(r,hi)][q = qg]
      f32x16 sc;
      __builtin_amdgcn_s_setprio(1);
      {
        const int r = g * 32 + l31;
        f32x16 a = {};
        #pragma unroll
        for (int ks2 = 0; ks2 < 4; ++ks2) {
          short8 kf = *(const short8*)&ks_[r * 64 + ((ks2 * 16 + hi * 8) ^ sx)];
          a = __builtin_amdgcn_mfma_f32_32x32x16_bf16(kf, qf[ks2], a, 0, 0, 0);
        }
        sc = a;
      }
      __builtin_amdgcn_s_setprio(0);

      if (t == ntiles - 1) {
        #pragma unroll
        for (int r = 0; r < 16; ++r) {
          const int kvg = k0 + g * 32 + (r & 3) + 8 * (r >> 2) + 4 * hi;
          if (kvg > qg) sc[r] = -1e30f;
        }
      }

      // no-max softmax: p = exp2(s); PV A-frags in-register (T12):
      // af[st] = P[q=l31][kv_local = st*16 + hi*8 + j] within the 32-quarter
      short8 af[2];
      {
        #pragma unroll
        for (int r = 0; r < 16; ++r) sc[r] = exp2f(sc[r]);
        la0 += (sc[0] + sc[1]) + (sc[2] + sc[3]);
        la1 += (sc[4] + sc[5]) + (sc[6] + sc[7]);
        la2 += (sc[8] + sc[9]) + (sc[10] + sc[11]);
        la3 += (sc[12] + sc[13]) + (sc[14] + sc[15]);
        #pragma unroll
        for (int st = 0; st < 2; ++st) {
          uint32_t x0 = pk2(sc[st * 8 + 0], sc[st * 8 + 1]);
          uint32_t x1 = pk2(sc[st * 8 + 2], sc[st * 8 + 3]);
          uint32_t x2 = pk2(sc[st * 8 + 4], sc[st * 8 + 5]);
          uint32_t x3 = pk2(sc[st * 8 + 6], sc[st * 8 + 7]);
          asm("v_permlane32_swap_b32 %0, %1" : "+v"(x0), "+v"(x2));
          asm("v_permlane32_swap_b32 %0, %1" : "+v"(x1), "+v"(x3));
          union { short8 s8; uint32_t u[4]; } cv;
          cv.u[0] = x0; cv.u[1] = x1; cv.u[2] = x2; cv.u[3] = x3;
          af[st] = cv.s8;
        }
      }

      // O += P V over the 32-kv quarter: B-frag from V^T LDS rows d=l31 / 32+l31
      __builtin_amdgcn_s_setprio(1);
      #pragma unroll
      for (int s = 0; s < 2; ++s) {
        const int co = g * 32 + s * 16 + hi * 8;
        short8 bv0 = *(const short8*)&vs_[l31 * 128 + (co ^ sx)];
        O0 = __builtin_amdgcn_mfma_f32_32x32x16_bf16(af[s], bv0, O0, 0, 0, 0);
        short8 bv1 = *(const short8*)&vs_[(32 + l31) * 128 + (co ^ sx)];
        O1 = __builtin_amdgcn_mfma_f32_32x32x16_bf16(af[s], bv1, O1, 0, 0, 0);
      }
      __builtin_amdgcn_s_setprio(0);

      __syncthreads();   // drains staged t+1 loads + buffer handoff
    }

    // ---- combine the four kv quarters (linear: no-max softmax, no rescale) ----
    float ll = (la0 + la1) + (la2 + la3);
    ll += __shfl_xor(ll, 32, 64);   // lane: l for q=l31 over this wave's kv set

    float* Os = (float*)SMEM;                     // [qs 2][src 3][lane 64][33]
    float* Ls = (float*)SMEM + 2 * 3 * 64 * 33;   // [qs 2][src 3][lane 64]
    if (g > 0) {
      float* op = &Os[((qs * 3 + (g - 1)) * 64 + lane) * 33];
      #pragma unroll
      for (int r = 0; r < 16; ++r) { op[r] = O0[r]; op[16 + r] = O1[r]; }
      Ls[(qs * 3 + (g - 1)) * 64 + lane] = ll;
    }
    __syncthreads();
    if (g == 0) {
      #pragma unroll
      for (int src = 0; src < 3; ++src) {
        const float* op = &Os[((qs * 3 + src) * 64 + lane) * 33];
        #pragma unroll
        for (int r = 0; r < 16; ++r) { O0[r] += op[r]; O1[r] += op[16 + r]; }
        ll += Ls[(qs * 3 + src) * 64 + lane];
      }
      const float inv = 1.0f / ll;
      #pragma unroll
      for (int r = 0; r < 16; ++r) {
        const int crow = (r & 3) + 8 * (r >> 2) + 4 * hi;
        const float invr = __shfl(inv, crow, 64);
        const size_t o = qbase + (size_t)(q0 + qs * 32 + crow) * 1024 + h * 64;
        Ctx[o + l31]      = f2bf(O0[r] * invr);
        Ctx[o + 32 + l31] = f2bf(O1[r] * invr);
      }
    }
    __syncthreads();   // scratch dead before next half's STAGE overwrites it
  }
#undef STAGE
}

extern "C" void kernel_launch(void* const* d_in, const int* in_sizes, int n_in,
                              void* d_out, int out_size, void* d_ws, size_t ws_size,
                              hipStream_t stream) {
  const float* x  = (const float*)d_in[0];
  const float* Wq = (const float*)d_in[1];
  const float* Wk = (const float*)d_in[2];
  const float* Wv = (const float*)d_in[3];
  const float* Wo = (const float*)d_in[4];
  float* out = (float*)d_out;

  char* w = (char*)d_ws;
  short* Xb    = (short*)w;  w += (size_t)MROWS * DM * 2;
  short* WcatT = (short*)w;  w += (size_t)NQKV * DM * 2;
  short* WoT   = (short*)w;  w += (size_t)DM * DM * 2;
  float* QKVf  = (float*)w;  w += (size_t)MROWS * NQKV * 4;
  short* Qbuf  = (short*)w;  w += (size_t)MROWS * DM * 2;
  short* Kbuf  = (short*)w;  w += (size_t)MROWS * 256 * 2;
  short* Vbuf  = (short*)w;  w += (size_t)MROWS * 256 * 2;
  short* Vt    = (short*)w;  w += (size_t)8 * 64 * S_LEN * 2;
  short* Ctx   = (short*)QKVf;   // QKVf dead after rope

  f32_to_bf16_vec<<<dim3(4096), dim3(256), 0, stream>>>(x, Xb, MROWS * DM / 4);
  transpose_f32_bf16<<<dim3(16, 16), dim3(256), 0, stream>>>(Wq, WcatT, 1024, 1024);
  transpose_f32_bf16<<<dim3(16, 4),  dim3(256), 0, stream>>>(Wk, WcatT + (size_t)1024*1024, 1024, 256);
  transpose_f32_bf16<<<dim3(16, 4),  dim3(256), 0, stream>>>(Wv, WcatT + (size_t)1280*1024, 1024, 256);
  transpose_f32_bf16<<<dim3(16, 16), dim3(256), 0, stream>>>(Wo, WoT, 1024, 1024);

  // 64x128 tiles: gemm1 grid 768 (3 blocks/CU), gemm2 grid 512 (2 blocks/CU)
  gemm_bf16_t<64,128><<<dim3(NQKV / 128, MROWS / 64), dim3(256), 0, stream>>>(Xb, WcatT, QKVf, MROWS, NQKV, DM);
  rope_kernel<<<dim3(MROWS), dim3(256), 0, stream>>>(QKVf, Qbuf, Kbuf, Vbuf);
  transpose_v<<<dim3(32, 8), dim3(256), 0, stream>>>(Vbuf, Vt);
  fattn9<<<dim3(512), dim3(512), 0, stream>>>(Qbuf, Kbuf, Vt, Ctx);
  gemm_bf16_t<64,128><<<dim3(DM / 128, MROWS / 64), dim3(256), 0, stream>>>(Ctx, WoT, out, MROWS, DM, DM);
}

// Round 4
// 178.402 us; speedup vs baseline: 1.1605x; 1.0384x over previous
//
#include <hip/hip_runtime.h>
#include <hip/hip_bf16.h>
#include <cstdint>
#include <math.h>

#define S_LEN 2048
#define DM 1024
#define NQKV 1536
#define MROWS 4096   // B * S
#define BKT 64

typedef __attribute__((ext_vector_type(8))) short short8;
typedef __attribute__((ext_vector_type(4))) float f32x4;
typedef __attribute__((ext_vector_type(16))) float f32x16;

// 0.125 (1/sqrt(64)) * log2(e), folded into Q at RoPE time
#define QFOLD 0.18033688011112042f

__device__ __forceinline__ short f2bf(float x) {
  union { float f; uint32_t u; } v; v.f = x;
  uint32_t r = (v.u + 0x7fffu + ((v.u >> 16) & 1u)) >> 16;
  return (short)(uint16_t)r;
}

__device__ __forceinline__ uint32_t pk2(float a, float b) {
  __hip_bfloat162 h = __float22bfloat162_rn(make_float2(a, b));
  union { __hip_bfloat162 h2; uint32_t u; } cv; cv.h2 = h;
  return cv.u;
}

// ---------------- merged prep: x->bf16 convert + 4 weight transposes ----------------
// one launch instead of five; branches are per-block (no divergent barriers).
// blocks [0,4096): convert; [4096,4352): Wq; [4352,4416): Wk; [4416,4480): Wv;
// [4480,4736): Wo.
__global__ __launch_bounds__(256) void prep(const float* __restrict__ x,
    const float* __restrict__ Wq, const float* __restrict__ Wk,
    const float* __restrict__ Wv, const float* __restrict__ Wo,
    short* __restrict__ Xb, short* __restrict__ WcatT, short* __restrict__ WoT) {
  __shared__ short T[64 * 72];
  const int bb = blockIdx.x;
  const int tid = threadIdx.x;
  if (bb < 4096) {                       // fp32 -> bf16 vectorized convert
    const int i = bb * 256 + tid;        // exactly MROWS*DM/4 elements
    float4 v = ((const float4*)x)[i];
    short4 o;
    o.x = f2bf(v.x); o.y = f2bf(v.y); o.z = f2bf(v.z); o.w = f2bf(v.w);
    ((short4*)Xb)[i] = o;
    return;
  }
  const float* src; short* dst; int R, C, t2 = bb - 4096;
  if (t2 < 256)      { src = Wq; dst = WcatT;                        R = 1024; C = 1024; }
  else if (t2 < 320) { t2 -= 256; src = Wk; dst = WcatT + (size_t)1024*1024; R = 1024; C = 256; }
  else if (t2 < 384) { t2 -= 320; src = Wv; dst = WcatT + (size_t)1280*1024; R = 1024; C = 256; }
  else               { t2 -= 384; src = Wo; dst = WoT;               R = 1024; C = 1024; }
  const int r0 = (t2 & 15) * 64, c0 = (t2 >> 4) * 64;
  #pragma unroll
  for (int i = 0; i < 4; ++i) {
    int chunk = tid + i * 256;
    int r = chunk >> 4, cc = (chunk & 15) * 4;
    float4 v = *(const float4*)&src[(size_t)(r0 + r) * C + c0 + cc];
    T[(cc + 0) * 72 + r] = f2bf(v.x);
    T[(cc + 1) * 72 + r] = f2bf(v.y);
    T[(cc + 2) * 72 + r] = f2bf(v.z);
    T[(cc + 3) * 72 + r] = f2bf(v.w);
  }
  __syncthreads();
  #pragma unroll
  for (int i = 0; i < 2; ++i) {
    int chunk = tid + i * 256;
    int rr = chunk >> 3, kk = (chunk & 7) * 8;
    *(uint4*)&dst[(size_t)(c0 + rr) * R + r0 + kk] = *(uint4*)&T[rr * 72 + kk];
  }
}

// ---------------- bf16 MFMA GEMM, m97-style staging, tile-templated ----------------
template<int BMT, int BNT>
__global__ __launch_bounds__(256) void gemm_bf16_t(const short* __restrict__ A,
    const short* __restrict__ BT, float* __restrict__ C, int M, int N, int K) {
  constexpr int MI = BMT / 32, NI = BNT / 32;
  __shared__ short As[BMT * BKT];
  __shared__ short Bs[BNT * BKT];
  const int tid = threadIdx.x;
  const int wave = tid >> 6, lane = tid & 63;
  const int quad = lane >> 4, l15 = lane & 15;
  const int wm = (wave >> 1) * (BMT / 2), wn = (wave & 1) * (BNT / 2);
  const int m0 = blockIdx.y * BMT, n0 = blockIdx.x * BNT;
  const int rA = wave * (BMT / 4) + (lane >> 3);
  const int rB = wave * (BNT / 4) + (lane >> 3);
  const int scol = (lane & 7) * 8;

  f32x4 acc[MI][NI] = {};

  for (int k0 = 0; k0 < K; k0 += BKT) {
    __syncthreads();
    #pragma unroll
    for (int j = 0; j < MI; ++j)
      __builtin_amdgcn_global_load_lds(
          (const __attribute__((address_space(1))) void*)&A[(size_t)(m0 + rA + j * 8) * K + k0 + scol],
          (__attribute__((address_space(3))) void*)&As[(wave * MI + j) * 512],
          16, 0, 0);
    #pragma unroll
    for (int j = 0; j < NI; ++j)
      __builtin_amdgcn_global_load_lds(
          (const __attribute__((address_space(1))) void*)&BT[(size_t)(n0 + rB + j * 8) * K + k0 + scol],
          (__attribute__((address_space(3))) void*)&Bs[(wave * NI + j) * 512],
          16, 0, 0);
    __syncthreads();
    #pragma unroll
    for (int ks = 0; ks < 2; ++ks) {
      short8 af[MI], bfr[NI];
      #pragma unroll
      for (int mi = 0; mi < MI; ++mi)
        af[mi] = *(const short8*)&As[(wm + mi*16 + l15)*BKT + ks*32 + quad*8];
      #pragma unroll
      for (int ni = 0; ni < NI; ++ni)
        bfr[ni] = *(const short8*)&Bs[(wn + ni*16 + l15)*BKT + ks*32 + quad*8];
      #pragma unroll
      for (int mi = 0; mi < MI; ++mi)
        #pragma unroll
        for (int ni = 0; ni < NI; ++ni)
          acc[mi][ni] = __builtin_amdgcn_mfma_f32_16x16x32_bf16(af[mi], bfr[ni], acc[mi][ni], 0, 0, 0);
    }
  }
  #pragma unroll
  for (int mi = 0; mi < MI; ++mi)
    #pragma unroll
    for (int ni = 0; ni < NI; ++ni)
      #pragma unroll
      for (int r = 0; r < 4; ++r)
        C[(size_t)(m0 + wm + mi*16 + quad*4 + r)*N + (n0 + wn + ni*16 + l15)] = acc[mi][ni][r];
}

// ---------------- RoPE + bf16 pack; Q gets scale*log2e folded in ----------------
// K rows written XOR-swizzled within each 64-short head segment: j -> j^((s&7)<<3),
// so fattn's ds_read_b128 of K is conflict-free with linear global_load_lds staging.
__global__ void rope_kernel(const float* __restrict__ qkv, short* __restrict__ Qb,
                            short* __restrict__ Kb, short* __restrict__ Vb) {
  __shared__ float csn[64];
  const int row = blockIdx.x;
  const int s = row & (S_LEN - 1);
  const int tid = threadIdx.x;
  const float* rp = qkv + (size_t)row * NQKV;
  if (tid < 32) {
    float inv = exp2f(-(float)tid * 0.41524101186092029f);  // log2(10000)/32
    float ang = (float)s * inv;
    csn[tid] = cosf(ang);
    csn[tid + 32] = sinf(ang);
  }
  __syncthreads();
  #pragma unroll
  for (int i = 0; i < 2; ++i) {
    int p = tid + i * 256;
    int hh = p >> 5, j = p & 31;
    float cs = csn[j], sn = csn[j + 32];
    float x1 = rp[hh*64 + j], x2 = rp[hh*64 + j + 32];
    Qb[(size_t)row*1024 + hh*64 + j]      = f2bf((x1*cs - x2*sn) * QFOLD);
    Qb[(size_t)row*1024 + hh*64 + j + 32] = f2bf((x2*cs + x1*sn) * QFOLD);
  }
  if (tid < 128) {
    int hh = tid >> 5, j = tid & 31;
    float cs = csn[j], sn = csn[j + 32];
    float x1 = rp[1024 + hh*64 + j], x2 = rp[1024 + hh*64 + j + 32];
    const int sw = (s & 7) << 3;
    Kb[(size_t)row*256 + hh*64 + (j ^ sw)]        = f2bf(x1*cs - x2*sn);
    Kb[(size_t)row*256 + hh*64 + ((j + 32) ^ sw)] = f2bf(x2*cs + x1*sn);
  }
  Vb[(size_t)row*256 + tid] = f2bf(rp[1280 + tid]);
}

// ---------------- V transpose: Vb[b*S+s][kvh*64+d] -> Vt[(b*4+kvh)*64+d][s] ----------------
// Vt rows written XOR-swizzled within each 64-element kv chunk: s -> s^((d&7)<<3).
__global__ __launch_bounds__(256) void transpose_v(const short* __restrict__ Vb,
                                                   short* __restrict__ Vt) {
  __shared__ short T[64 * 72];
  const int s0 = blockIdx.x * 64;
  const int bh = blockIdx.y;
  const int b = bh >> 2, kvh = bh & 3;
  const int tid = threadIdx.x;
  #pragma unroll
  for (int i = 0; i < 2; ++i) {
    int chunk = tid + i * 256;
    int r = chunk >> 3, c = (chunk & 7) * 8;
    short8 v = *(const short8*)&Vb[(size_t)(b*S_LEN + s0 + r)*256 + kvh*64 + c];
    #pragma unroll
    for (int t = 0; t < 8; ++t) T[(c + t) * 72 + r] = v[t];
  }
  __syncthreads();
  #pragma unroll
  for (int i = 0; i < 2; ++i) {
    int chunk = tid + i * 256;
    int rr = chunk >> 3, kk = (chunk & 7) * 8;
    *(uint4*)&Vt[(size_t)(bh*64 + rr)*S_LEN + s0 + (kk ^ ((rr & 7) << 3))] = *(uint4*)&T[rr * 72 + kk];
  }
}

// ---------------- causal GQA flash attention v10: counted-vmcnt 4-deep pipeline ----------------
// grid 512 = (b:2, h:16, pair:16). Block = 256 threads = 4 waves:
//   qs = wav&1 -> q-subtile of 32; g = wav>>1 -> kv half (32 rows) of a 64-kv unit.
// 64-kv units, FOUR 16KB LDS buffers (64KB -> 2 blocks/CU). T3+T4 schedule:
// per unit: s_waitcnt vmcnt(counted) -> raw s_barrier -> issue STAGE(t+3) ->
// compute. Loads get ~3 units of compute to land; the barrier never drains the
// prefetch queue (avoids the __syncthreads vmcnt(0) structural stall).
// STAGE(t+3) writes buf[(t-1)&3], safe: barrier at top of t proves all waves
// finished reading it in iteration t-1.
__global__ __launch_bounds__(256, 2) void fattn10(const short* __restrict__ Qb,
    const short* __restrict__ Kb, const short* __restrict__ Vt, short* __restrict__ Ctx) {
  __shared__ short SMEM[32768];   // 4 bufs x (K[64][64] @ +0, VT[64][64] @ +4096)
  const int idx = blockIdx.x;
  const int pi  = idx & 15;
  const int h   = (idx >> 4) & 15;
  const int b   = idx >> 8;
  const int kvh = h >> 2;
  const int tid = threadIdx.x, wav = tid >> 6, lane = tid & 63;
  const int l31 = lane & 31, hi = lane >> 5;
  const int qs = wav & 1, g = wav >> 1;    // g in {0,1}
  const int sx = (l31 & 7) << 3;           // XOR-swizzle key (matches producers)
  const size_t qbase  = (size_t)b * S_LEN * 1024;
  const size_t kbase  = (size_t)b * S_LEN * 256;
  const size_t vtbase = (size_t)(b * 4 + kvh) * 64 * S_LEN;

  // staging: wave w stages K rows [w*16,+16) and V d-rows [w*16,+16) of each
  // 64-kv unit; 2+2 width-16 global_load_lds per wave per unit; linear LDS
  // dest (rule #21: producers pre-swizzled the data).
  const short* kptr = Kb + kbase + (size_t)(wav * 16 + (lane >> 3)) * 256 + kvh * 64 + (lane & 7) * 8;
  const short* vptr = Vt + vtbase + (size_t)(wav * 16 + (lane >> 3)) * 2048 + (lane & 7) * 8;

#define STAGE(u) do { \
    const int bi_ = (u) & 3; \
    const short* kp_ = kptr + (size_t)(u) * 16384; \
    const short* vp_ = vptr + (u) * 64; \
    short* kd_ = &SMEM[bi_ * 8192 + wav * 1024]; \
    short* vd_ = &SMEM[bi_ * 8192 + 4096 + wav * 1024]; \
    _Pragma("unroll") \
    for (int i_ = 0; i_ < 2; ++i_) { \
      __builtin_amdgcn_global_load_lds((const __attribute__((address_space(1))) void*)(kp_ + i_ * 2048), \
          (__attribute__((address_space(3))) void*)(kd_ + i_ * 512), 16, 0, 0); \
      __builtin_amdgcn_global_load_lds((const __attribute__((address_space(1))) void*)(vp_ + i_ * 16384), \
          (__attribute__((address_space(3))) void*)(vd_ + i_ * 512), 16, 0, 0); \
    } \
  } while (0)

  for (int half = 0; half < 2; ++half) {
    const int jt = half ? (31 - pi) : pi;
    const int q0 = jt * 64;
    const int ntiles = jt + 1;            // 64-kv units; pair sums to 34, uniform
    const int qg = q0 + qs * 32 + l31;    // this lane's q column

    // Q B-frags: lane holds Q[q=l31 of subtile][d = ks*16 + hi*8 + j]
    short8 qf[4];
    {
      const short* qp = &Qb[qbase + (size_t)qg * 1024 + h * 64 + hi * 8];
      #pragma unroll
      for (int ks = 0; ks < 4; ++ks) qf[ks] = *(const short8*)(qp + ks * 16);
    }

    f32x16 O0 = {}, O1 = {};
    float la0 = 0.f, la1 = 0.f, la2 = 0.f, la3 = 0.f;

    STAGE(0);
    if (ntiles > 1) STAGE(1);
    if (ntiles > 2) STAGE(2);

    for (int t = 0; t < ntiles; ++t) {
      const int k0 = t * 64;
      const int rem = ntiles - 1 - t;
      // allow loads for the next min(rem,2) prefetched units to stay in flight
      if (rem >= 2)      { asm volatile("s_waitcnt vmcnt(8)" ::: "memory"); }
      else if (rem == 1) { asm volatile("s_waitcnt vmcnt(4)" ::: "memory"); }
      else               { asm volatile("s_waitcnt vmcnt(0)" ::: "memory"); }
      __builtin_amdgcn_sched_barrier(0);
      __builtin_amdgcn_s_barrier();
      if (t + 3 < ntiles) STAGE(t + 3);

      const short* ks_ = &SMEM[(t & 3) * 8192];
      const short* vs_ = &SMEM[(t & 3) * 8192 + 4096];

      // St = K Q^T over this wave's 32-kv half: sc[r] = S[kv=k0+g*32+crow(r,hi)][q=qg]
      f32x16 sc;
      __builtin_amdgcn_s_setprio(1);
      {
        const int r = g * 32 + l31;
        f32x16 a = {};
        #pragma unroll
        for (int ks2 = 0; ks2 < 4; ++ks2) {
          short8 kf = *(const short8*)&ks_[r * 64 + ((ks2 * 16 + hi * 8) ^ sx)];
          a = __builtin_amdgcn_mfma_f32_32x32x16_bf16(kf, qf[ks2], a, 0, 0, 0);
        }
        sc = a;
      }
      __builtin_amdgcn_s_setprio(0);

      if (t == ntiles - 1) {
        #pragma unroll
        for (int r = 0; r < 16; ++r) {
          const int kvg = k0 + g * 32 + (r & 3) + 8 * (r >> 2) + 4 * hi;
          if (kvg > qg) sc[r] = -1e30f;
        }
      }

      // no-max softmax: p = exp2(s); PV A-frags in-register (T12)
      short8 af[2];
      {
        #pragma unroll
        for (int r = 0; r < 16; ++r) sc[r] = exp2f(sc[r]);
        la0 += (sc[0] + sc[1]) + (sc[2] + sc[3]);
        la1 += (sc[4] + sc[5]) + (sc[6] + sc[7]);
        la2 += (sc[8] + sc[9]) + (sc[10] + sc[11]);
        la3 += (sc[12] + sc[13]) + (sc[14] + sc[15]);
        #pragma unroll
        for (int st = 0; st < 2; ++st) {
          uint32_t x0 = pk2(sc[st * 8 + 0], sc[st * 8 + 1]);
          uint32_t x1 = pk2(sc[st * 8 + 2], sc[st * 8 + 3]);
          uint32_t x2 = pk2(sc[st * 8 + 4], sc[st * 8 + 5]);
          uint32_t x3 = pk2(sc[st * 8 + 6], sc[st * 8 + 7]);
          asm("v_permlane32_swap_b32 %0, %1" : "+v"(x0), "+v"(x2));
          asm("v_permlane32_swap_b32 %0, %1" : "+v"(x1), "+v"(x3));
          union { short8 s8; uint32_t u[4]; } cv;
          cv.u[0] = x0; cv.u[1] = x1; cv.u[2] = x2; cv.u[3] = x3;
          af[st] = cv.s8;
        }
      }

      // O += P V over the 32-kv half: B-frag from V^T LDS rows d=l31 / 32+l31
      __builtin_amdgcn_s_setprio(1);
      #pragma unroll
      for (int s2 = 0; s2 < 2; ++s2) {
        const int co = g * 32 + s2 * 16 + hi * 8;
        short8 bv0 = *(const short8*)&vs_[l31 * 64 + (co ^ sx)];
        O0 = __builtin_amdgcn_mfma_f32_32x32x16_bf16(af[s2], bv0, O0, 0, 0, 0);
        short8 bv1 = *(const short8*)&vs_[(32 + l31) * 64 + (co ^ sx)];
        O1 = __builtin_amdgcn_mfma_f32_32x32x16_bf16(af[s2], bv1, O1, 0, 0, 0);
      }
      __builtin_amdgcn_s_setprio(0);
    }

    // ---- combine the two kv halves (linear: no-max softmax, no rescale) ----
    float ll = (la0 + la1) + (la2 + la3);
    ll += __shfl_xor(ll, 32, 64);   // lane: l for q=l31 over this wave's kv set
    __syncthreads();                // all waves done reading K/V buffers

    float* Os = (float*)SMEM;                 // [qs 2][lane 64][33] padded
    float* Ls = (float*)SMEM + 2 * 64 * 33;   // [qs 2][lane 64]
    if (g == 1) {
      float* op = &Os[(qs * 64 + lane) * 33];
      #pragma unroll
      for (int r = 0; r < 16; ++r) { op[r] = O0[r]; op[16 + r] = O1[r]; }
      Ls[qs * 64 + lane] = ll;
    }
    __syncthreads();
    if (g == 0) {
      const float* op = &Os[(qs * 64 + lane) * 33];
      ll += Ls[qs * 64 + lane];
      #pragma unroll
      for (int r = 0; r < 16; ++r) { O0[r] += op[r]; O1[r] += op[16 + r]; }
      const float inv = 1.0f / ll;
      #pragma unroll
      for (int r = 0; r < 16; ++r) {
        const int crow = (r & 3) + 8 * (r >> 2) + 4 * hi;
        const float invr = __shfl(inv, crow, 64);
        const size_t o = qbase + (size_t)(q0 + qs * 32 + crow) * 1024 + h * 64;
        Ctx[o + l31]      = f2bf(O0[r] * invr);
        Ctx[o + 32 + l31] = f2bf(O1[r] * invr);
      }
    }
    __syncthreads();   // scratch dead before next half's STAGE overwrites it
  }
#undef STAGE
}

extern "C" void kernel_launch(void* const* d_in, const int* in_sizes, int n_in,
                              void* d_out, int out_size, void* d_ws, size_t ws_size,
                              hipStream_t stream) {
  const float* x  = (const float*)d_in[0];
  const float* Wq = (const float*)d_in[1];
  const float* Wk = (const float*)d_in[2];
  const float* Wv = (const float*)d_in[3];
  const float* Wo = (const float*)d_in[4];
  float* out = (float*)d_out;

  char* w = (char*)d_ws;
  short* Xb    = (short*)w;  w += (size_t)MROWS * DM * 2;
  short* WcatT = (short*)w;  w += (size_t)NQKV * DM * 2;
  short* WoT   = (short*)w;  w += (size_t)DM * DM * 2;
  float* QKVf  = (float*)w;  w += (size_t)MROWS * NQKV * 4;
  short* Qbuf  = (short*)w;  w += (size_t)MROWS * DM * 2;
  short* Kbuf  = (short*)w;  w += (size_t)MROWS * 256 * 2;
  short* Vbuf  = (short*)w;  w += (size_t)MROWS * 256 * 2;
  short* Vt    = (short*)w;  w += (size_t)8 * 64 * S_LEN * 2;
  short* Ctx   = (short*)QKVf;   // QKVf dead after rope

  prep<<<dim3(4736), dim3(256), 0, stream>>>(x, Wq, Wk, Wv, Wo, Xb, WcatT, WoT);

  // 64x128 tiles: gemm1 grid 768 (3 blocks/CU), gemm2 grid 512 (2 blocks/CU)
  gemm_bf16_t<64,128><<<dim3(NQKV / 128, MROWS / 64), dim3(256), 0, stream>>>(Xb, WcatT, QKVf, MROWS, NQKV, DM);
  rope_kernel<<<dim3(MROWS), dim3(256), 0, stream>>>(QKVf, Qbuf, Kbuf, Vbuf);
  transpose_v<<<dim3(32, 8), dim3(256), 0, stream>>>(Vbuf, Vt);
  fattn10<<<dim3(512), dim3(256), 0, stream>>>(Qbuf, Kbuf, Vt, Ctx);
  gemm_bf16_t<64,128><<<dim3(DM / 128, MROWS / 64), dim3(256), 0, stream>>>(Ctx, WoT, out, MROWS, DM, DM);
}

// Round 5
// 164.533 us; speedup vs baseline: 1.2583x; 1.0843x over previous
//
#include <hip/hip_runtime.h>
#include <hip/hip_bf16.h>
#include <cstdint>
#include <math.h>

#define S_LEN 2048
#define DM 1024
#define NQKV 1536
#define MROWS 4096   // B * S
#define BKT 64

typedef __attribute__((ext_vector_type(8))) short short8;
typedef __attribute__((ext_vector_type(4))) float f32x4;
typedef __attribute__((ext_vector_type(16))) float f32x16;

// 0.125 (1/sqrt(64)) * log2(e), folded into Q at RoPE time
#define QFOLD 0.18033688011112042f

__device__ __forceinline__ short f2bf(float x) {
  union { float f; uint32_t u; } v; v.f = x;
  uint32_t r = (v.u + 0x7fffu + ((v.u >> 16) & 1u)) >> 16;
  return (short)(uint16_t)r;
}

__device__ __forceinline__ uint32_t pk2(float a, float b) {
  __hip_bfloat162 h = __float22bfloat162_rn(make_float2(a, b));
  union { __hip_bfloat162 h2; uint32_t u; } cv; cv.h2 = h;
  return cv.u;
}

// ---------------- merged prep: x->bf16 convert + 4 weight transposes + rope table ----------------
// blocks [0,4096): convert; [4096,4352): Wq; [4352,4416): Wk; [4416,4480): Wv;
// [4480,4736): Wo; [4736,4800): cos/sin table tab[s*32+j] (same cosf/sinf as the
// old rope kernel -> bit-identical rope values when applied in the GEMM epilogue).
__global__ __launch_bounds__(256) void prep(const float* __restrict__ x,
    const float* __restrict__ Wq, const float* __restrict__ Wk,
    const float* __restrict__ Wv, const float* __restrict__ Wo,
    short* __restrict__ Xb, short* __restrict__ WcatT, short* __restrict__ WoT,
    float2* __restrict__ tab) {
  __shared__ short T[64 * 72];
  const int bb = blockIdx.x;
  const int tid = threadIdx.x;
  if (bb < 4096) {                       // fp32 -> bf16 vectorized convert
    const int i = bb * 256 + tid;        // exactly MROWS*DM/4 elements
    float4 v = ((const float4*)x)[i];
    short4 o;
    o.x = f2bf(v.x); o.y = f2bf(v.y); o.z = f2bf(v.z); o.w = f2bf(v.w);
    ((short4*)Xb)[i] = o;
    return;
  }
  if (bb >= 4736) {                      // rope cos/sin table: 2048 x 32 entries
    const int gid = (bb - 4736) * 256 + tid;   // [0,16384)
    #pragma unroll
    for (int e = 0; e < 4; ++e) {
      const int ii = gid + e * 16384;          // [0,65536)
      const int s = ii >> 5, j = ii & 31;
      const float inv = exp2f(-(float)j * 0.41524101186092029f);  // log2(10000)/32
      const float ang = (float)s * inv;
      tab[ii] = make_float2(cosf(ang), sinf(ang));
    }
    return;
  }
  const float* src; short* dst; int R, C, t2 = bb - 4096;
  if (t2 < 256)      { src = Wq; dst = WcatT;                        R = 1024; C = 1024; }
  else if (t2 < 320) { t2 -= 256; src = Wk; dst = WcatT + (size_t)1024*1024; R = 1024; C = 256; }
  else if (t2 < 384) { t2 -= 320; src = Wv; dst = WcatT + (size_t)1280*1024; R = 1024; C = 256; }
  else               { t2 -= 384; src = Wo; dst = WoT;               R = 1024; C = 1024; }
  const int r0 = (t2 & 15) * 64, c0 = (t2 >> 4) * 64;
  #pragma unroll
  for (int i = 0; i < 4; ++i) {
    int chunk = tid + i * 256;
    int r = chunk >> 4, cc = (chunk & 15) * 4;
    float4 v = *(const float4*)&src[(size_t)(r0 + r) * C + c0 + cc];
    T[(cc + 0) * 72 + r] = f2bf(v.x);
    T[(cc + 1) * 72 + r] = f2bf(v.y);
    T[(cc + 2) * 72 + r] = f2bf(v.z);
    T[(cc + 3) * 72 + r] = f2bf(v.w);
  }
  __syncthreads();
  #pragma unroll
  for (int i = 0; i < 2; ++i) {
    int chunk = tid + i * 256;
    int rr = chunk >> 3, kk = (chunk & 7) * 8;
    *(uint4*)&dst[(size_t)(c0 + rr) * R + r0 + kk] = *(uint4*)&T[rr * 72 + kk];
  }
}

// ---------------- bf16 MFMA GEMM, m97-style staging, tile-templated (plain fp32 C) ----------------
template<int BMT, int BNT>
__global__ __launch_bounds__(256) void gemm_bf16_t(const short* __restrict__ A,
    const short* __restrict__ BT, float* __restrict__ C, int M, int N, int K) {
  constexpr int MI = BMT / 32, NI = BNT / 32;
  __shared__ short As[BMT * BKT];
  __shared__ short Bs[BNT * BKT];
  const int tid = threadIdx.x;
  const int wave = tid >> 6, lane = tid & 63;
  const int quad = lane >> 4, l15 = lane & 15;
  const int wm = (wave >> 1) * (BMT / 2), wn = (wave & 1) * (BNT / 2);
  const int m0 = blockIdx.y * BMT, n0 = blockIdx.x * BNT;
  const int rA = wave * (BMT / 4) + (lane >> 3);
  const int rB = wave * (BNT / 4) + (lane >> 3);
  const int scol = (lane & 7) * 8;

  f32x4 acc[MI][NI] = {};

  for (int k0 = 0; k0 < K; k0 += BKT) {
    __syncthreads();
    #pragma unroll
    for (int j = 0; j < MI; ++j)
      __builtin_amdgcn_global_load_lds(
          (const __attribute__((address_space(1))) void*)&A[(size_t)(m0 + rA + j * 8) * K + k0 + scol],
          (__attribute__((address_space(3))) void*)&As[(wave * MI + j) * 512],
          16, 0, 0);
    #pragma unroll
    for (int j = 0; j < NI; ++j)
      __builtin_amdgcn_global_load_lds(
          (const __attribute__((address_space(1))) void*)&BT[(size_t)(n0 + rB + j * 8) * K + k0 + scol],
          (__attribute__((address_space(3))) void*)&Bs[(wave * NI + j) * 512],
          16, 0, 0);
    __syncthreads();
    #pragma unroll
    for (int ks = 0; ks < 2; ++ks) {
      short8 af[MI], bfr[NI];
      #pragma unroll
      for (int mi = 0; mi < MI; ++mi)
        af[mi] = *(const short8*)&As[(wm + mi*16 + l15)*BKT + ks*32 + quad*8];
      #pragma unroll
      for (int ni = 0; ni < NI; ++ni)
        bfr[ni] = *(const short8*)&Bs[(wn + ni*16 + l15)*BKT + ks*32 + quad*8];
      #pragma unroll
      for (int mi = 0; mi < MI; ++mi)
        #pragma unroll
        for (int ni = 0; ni < NI; ++ni)
          acc[mi][ni] = __builtin_amdgcn_mfma_f32_16x16x32_bf16(af[mi], bfr[ni], acc[mi][ni], 0, 0, 0);
    }
  }
  #pragma unroll
  for (int mi = 0; mi < MI; ++mi)
    #pragma unroll
    for (int ni = 0; ni < NI; ++ni)
      #pragma unroll
      for (int r = 0; r < 4; ++r)
        C[(size_t)(m0 + wm + mi*16 + quad*4 + r)*N + (n0 + wn + ni*16 + l15)] = acc[mi][ni][r];
}

// ---------------- QKV GEMM with fused RoPE epilogue ----------------
// 64x128 tile. Col pairing (j, j+32) for rotate_half is closed within a thread:
// x1 = acc[mi][ni], x2 = acc[mi][ni+2] (ni in {0,1}). Epilogue writes bf16
// Qb (rope*QFOLD), Kb (rope, XOR-swizzled j^((s&7)<<3)), Vb directly —
// no fp32 QKV intermediate, no separate rope kernel.
__global__ __launch_bounds__(256, 3) void gemm_qkv(const short* __restrict__ A,
    const short* __restrict__ BT, const float2* __restrict__ tab,
    short* __restrict__ Qb, short* __restrict__ Kb, short* __restrict__ Vb) {
  constexpr int MI = 2, NI = 4;   // 64 x 128
  __shared__ short As[64 * BKT];
  __shared__ short Bs[128 * BKT];
  const int tid = threadIdx.x;
  const int wave = tid >> 6, lane = tid & 63;
  const int quad = lane >> 4, l15 = lane & 15;
  const int wm = (wave >> 1) * 32, wn = (wave & 1) * 64;
  const int m0 = blockIdx.y * 64, n0 = blockIdx.x * 128;
  const int rA = wave * 16 + (lane >> 3);
  const int rB = wave * 32 + (lane >> 3);
  const int scol = (lane & 7) * 8;

  f32x4 acc[MI][NI] = {};

  for (int k0 = 0; k0 < DM; k0 += BKT) {
    __syncthreads();
    #pragma unroll
    for (int j = 0; j < MI; ++j)
      __builtin_amdgcn_global_load_lds(
          (const __attribute__((address_space(1))) void*)&A[(size_t)(m0 + rA + j * 8) * DM + k0 + scol],
          (__attribute__((address_space(3))) void*)&As[(wave * MI + j) * 512],
          16, 0, 0);
    #pragma unroll
    for (int j = 0; j < NI; ++j)
      __builtin_amdgcn_global_load_lds(
          (const __attribute__((address_space(1))) void*)&BT[(size_t)(n0 + rB + j * 8) * DM + k0 + scol],
          (__attribute__((address_space(3))) void*)&Bs[(wave * NI + j) * 512],
          16, 0, 0);
    __syncthreads();
    #pragma unroll
    for (int ks = 0; ks < 2; ++ks) {
      short8 af[MI], bfr[NI];
      #pragma unroll
      for (int mi = 0; mi < MI; ++mi)
        af[mi] = *(const short8*)&As[(wm + mi*16 + l15)*BKT + ks*32 + quad*8];
      #pragma unroll
      for (int ni = 0; ni < NI; ++ni)
        bfr[ni] = *(const short8*)&Bs[(wn + ni*16 + l15)*BKT + ks*32 + quad*8];
      #pragma unroll
      for (int mi = 0; mi < MI; ++mi)
        #pragma unroll
        for (int ni = 0; ni < NI; ++ni)
          acc[mi][ni] = __builtin_amdgcn_mfma_f32_16x16x32_bf16(af[mi], bfr[ni], acc[mi][ni], 0, 0, 0);
    }
  }

  const int c0 = n0 + wn;                 // multiple of 64
  if (n0 < 1024) {                        // ---- Q: rope * QFOLD ----
    #pragma unroll
    for (int mi = 0; mi < MI; ++mi)
      #pragma unroll
      for (int r = 0; r < 4; ++r) {
        const int row = m0 + wm + mi*16 + quad*4 + r;
        const int s = row & (S_LEN - 1);
        #pragma unroll
        for (int ni = 0; ni < 2; ++ni) {
          const int j = ni*16 + l15;
          const float2 cn = tab[s*32 + j];
          const float x1 = acc[mi][ni][r], x2 = acc[mi][ni+2][r];
          Qb[(size_t)row*1024 + c0 + j]      = f2bf((x1*cn.x - x2*cn.y) * QFOLD);
          Qb[(size_t)row*1024 + c0 + j + 32] = f2bf((x2*cn.x + x1*cn.y) * QFOLD);
        }
      }
  } else if (n0 < 1280) {                 // ---- K: rope + XOR-swizzle ----
    const int hh = (c0 - 1024) >> 6;
    #pragma unroll
    for (int mi = 0; mi < MI; ++mi)
      #pragma unroll
      for (int r = 0; r < 4; ++r) {
        const int row = m0 + wm + mi*16 + quad*4 + r;
        const int s = row & (S_LEN - 1);
        const int sw = (s & 7) << 3;
        #pragma unroll
        for (int ni = 0; ni < 2; ++ni) {
          const int j = ni*16 + l15;
          const float2 cn = tab[s*32 + j];
          const float x1 = acc[mi][ni][r], x2 = acc[mi][ni+2][r];
          Kb[(size_t)row*256 + hh*64 + (j ^ sw)]        = f2bf(x1*cn.x - x2*cn.y);
          Kb[(size_t)row*256 + hh*64 + ((j + 32) ^ sw)] = f2bf(x2*cn.x + x1*cn.y);
        }
      }
  } else {                                // ---- V: straight bf16 ----
    #pragma unroll
    for (int mi = 0; mi < MI; ++mi)
      #pragma unroll
      for (int ni = 0; ni < NI; ++ni)
        #pragma unroll
        for (int r = 0; r < 4; ++r) {
          const int row = m0 + wm + mi*16 + quad*4 + r;
          Vb[(size_t)row*256 + (c0 - 1280) + ni*16 + l15] = f2bf(acc[mi][ni][r]);
        }
  }
}

// ---------------- V transpose: Vb[b*S+s][kvh*64+d] -> Vt[(b*4+kvh)*64+d][s] ----------------
// Vt rows written XOR-swizzled within each 64-element kv chunk: s -> s^((d&7)<<3).
__global__ __launch_bounds__(256) void transpose_v(const short* __restrict__ Vb,
                                                   short* __restrict__ Vt) {
  __shared__ short T[64 * 72];
  const int s0 = blockIdx.x * 64;
  const int bh = blockIdx.y;
  const int b = bh >> 2, kvh = bh & 3;
  const int tid = threadIdx.x;
  #pragma unroll
  for (int i = 0; i < 2; ++i) {
    int chunk = tid + i * 256;
    int r = chunk >> 3, c = (chunk & 7) * 8;
    short8 v = *(const short8*)&Vb[(size_t)(b*S_LEN + s0 + r)*256 + kvh*64 + c];
    #pragma unroll
    for (int t = 0; t < 8; ++t) T[(c + t) * 72 + r] = v[t];
  }
  __syncthreads();
  #pragma unroll
  for (int i = 0; i < 2; ++i) {
    int chunk = tid + i * 256;
    int rr = chunk >> 3, kk = (chunk & 7) * 8;
    *(uint4*)&Vt[(size_t)(bh*64 + rr)*S_LEN + s0 + (kk ^ ((rr & 7) << 3))] = *(uint4*)&T[rr * 72 + kk];
  }
}

// ---------------- causal GQA flash attention v11: single q-tile/block, ring-3, 3 blocks/CU ----------------
// grid 1024 = (h:16, b:2, jt:32 longest-first). Block = 256 threads = 4 waves:
//   qs = wav&1 -> q-subtile of 32; g = wav>>1 -> kv half (32 rows) of a 64-kv unit.
// LDS = 3 x 16KB ring (48KB) -> 3 blocks/CU = 12 waves/CU (3/SIMD). Counted
// vmcnt keeps 1-2 units of loads in flight across the barrier (never drains
// mid-loop). Longest blocks (jt=31) launch first -> stragglers fill the tail.
__global__ __launch_bounds__(256, 3) void fattn11(const short* __restrict__ Qb,
    const short* __restrict__ Kb, const short* __restrict__ Vt, short* __restrict__ Ctx) {
  __shared__ short SMEM[24576];   // 3 bufs x (K[64][64] @ +0, VT[64][64] @ +4096 shorts)
  const int idx = blockIdx.x;
  const int h   = idx & 15;
  const int b   = (idx >> 4) & 1;
  const int jt  = 31 - (idx >> 5);         // longest-first dispatch
  const int kvh = h >> 2;
  const int tid = threadIdx.x, wav = tid >> 6, lane = tid & 63;
  const int l31 = lane & 31, hi = lane >> 5;
  const int qs = wav & 1, g = wav >> 1;    // g in {0,1}
  const int sx = (l31 & 7) << 3;           // XOR-swizzle key (matches producers)
  const size_t qbase  = (size_t)b * S_LEN * 1024;
  const size_t kbase  = (size_t)b * S_LEN * 256;
  const size_t vtbase = (size_t)(b * 4 + kvh) * 64 * S_LEN;

  const short* kptr = Kb + kbase + (size_t)(wav * 16 + (lane >> 3)) * 256 + kvh * 64 + (lane & 7) * 8;
  const short* vptr = Vt + vtbase + (size_t)(wav * 16 + (lane >> 3)) * 2048 + (lane & 7) * 8;

#define STAGE(u) do { \
    const int bi_ = (u) % 3; \
    const short* kp_ = kptr + (size_t)(u) * 16384; \
    const short* vp_ = vptr + (u) * 64; \
    short* kd_ = &SMEM[bi_ * 8192 + wav * 1024]; \
    short* vd_ = &SMEM[bi_ * 8192 + 4096 + wav * 1024]; \
    _Pragma("unroll") \
    for (int i_ = 0; i_ < 2; ++i_) { \
      __builtin_amdgcn_global_load_lds((const __attribute__((address_space(1))) void*)(kp_ + i_ * 2048), \
          (__attribute__((address_space(3))) void*)(kd_ + i_ * 512), 16, 0, 0); \
      __builtin_amdgcn_global_load_lds((const __attribute__((address_space(1))) void*)(vp_ + i_ * 16384), \
          (__attribute__((address_space(3))) void*)(vd_ + i_ * 512), 16, 0, 0); \
    } \
  } while (0)

  const int q0 = jt * 64;
  const int ntiles = jt + 1;            // 64-kv units
  const int qg = q0 + qs * 32 + l31;    // this lane's q column

  // Q B-frags: lane holds Q[q=l31 of subtile][d = ks*16 + hi*8 + j]
  short8 qf[4];
  {
    const short* qp = &Qb[qbase + (size_t)qg * 1024 + h * 64 + hi * 8];
    #pragma unroll
    for (int ks = 0; ks < 4; ++ks) qf[ks] = *(const short8*)(qp + ks * 16);
  }

  f32x16 O0 = {}, O1 = {};
  float la0 = 0.f, la1 = 0.f, la2 = 0.f, la3 = 0.f;

  STAGE(0);
  if (ntiles > 1) STAGE(1);

  for (int t = 0; t < ntiles; ++t) {
    const int k0 = t * 64;
    const int rem = ntiles - 1 - t;
    // unit t must be complete; allow the next prefetched unit's 4 loads in flight
    if (rem >= 1) { asm volatile("s_waitcnt vmcnt(4)" ::: "memory"); }
    else          { asm volatile("s_waitcnt vmcnt(0)" ::: "memory"); }
    __builtin_amdgcn_sched_barrier(0);
    __builtin_amdgcn_s_barrier();
    if (t + 2 < ntiles) STAGE(t + 2);   // writes buf (t+2)%3 == (t-1)%3: reads done

    const short* ks_ = &SMEM[(t % 3) * 8192];
    const short* vs_ = &SMEM[(t % 3) * 8192 + 4096];

    // St = K Q^T over this wave's 32-kv half: sc[r] = S[kv=k0+g*32+crow(r,hi)][q=qg]
    f32x16 sc;
    __builtin_amdgcn_s_setprio(1);
    {
      const int r = g * 32 + l31;
      f32x16 a = {};
      #pragma unroll
      for (int ks2 = 0; ks2 < 4; ++ks2) {
        short8 kf = *(const short8*)&ks_[r * 64 + ((ks2 * 16 + hi * 8) ^ sx)];
        a = __builtin_amdgcn_mfma_f32_32x32x16_bf16(kf, qf[ks2], a, 0, 0, 0);
      }
      sc = a;
    }
    __builtin_amdgcn_s_setprio(0);

    if (t == ntiles - 1) {
      #pragma unroll
      for (int r = 0; r < 16; ++r) {
        const int kvg = k0 + g * 32 + (r & 3) + 8 * (r >> 2) + 4 * hi;
        if (kvg > qg) sc[r] = -1e30f;
      }
    }

    // no-max softmax: p = exp2(s); PV A-frags in-register (T12)
    short8 af[2];
    {
      #pragma unroll
      for (int r = 0; r < 16; ++r) sc[r] = exp2f(sc[r]);
      la0 += (sc[0] + sc[1]) + (sc[2] + sc[3]);
      la1 += (sc[4] + sc[5]) + (sc[6] + sc[7]);
      la2 += (sc[8] + sc[9]) + (sc[10] + sc[11]);
      la3 += (sc[12] + sc[13]) + (sc[14] + sc[15]);
      #pragma unroll
      for (int st = 0; st < 2; ++st) {
        uint32_t x0 = pk2(sc[st * 8 + 0], sc[st * 8 + 1]);
        uint32_t x1 = pk2(sc[st * 8 + 2], sc[st * 8 + 3]);
        uint32_t x2 = pk2(sc[st * 8 + 4], sc[st * 8 + 5]);
        uint32_t x3 = pk2(sc[st * 8 + 6], sc[st * 8 + 7]);
        asm("v_permlane32_swap_b32 %0, %1" : "+v"(x0), "+v"(x2));
        asm("v_permlane32_swap_b32 %0, %1" : "+v"(x1), "+v"(x3));
        union { short8 s8; uint32_t u[4]; } cv;
        cv.u[0] = x0; cv.u[1] = x1; cv.u[2] = x2; cv.u[3] = x3;
        af[st] = cv.s8;
      }
    }

    // O += P V over the 32-kv half: B-frag from V^T LDS rows d=l31 / 32+l31
    __builtin_amdgcn_s_setprio(1);
    #pragma unroll
    for (int s2 = 0; s2 < 2; ++s2) {
      const int co = g * 32 + s2 * 16 + hi * 8;
      short8 bv0 = *(const short8*)&vs_[l31 * 64 + (co ^ sx)];
      O0 = __builtin_amdgcn_mfma_f32_32x32x16_bf16(af[s2], bv0, O0, 0, 0, 0);
      short8 bv1 = *(const short8*)&vs_[(32 + l31) * 64 + (co ^ sx)];
      O1 = __builtin_amdgcn_mfma_f32_32x32x16_bf16(af[s2], bv1, O1, 0, 0, 0);
    }
    __builtin_amdgcn_s_setprio(0);
  }

  // ---- combine the two kv halves (linear: no-max softmax, no rescale) ----
  float ll = (la0 + la1) + (la2 + la3);
  ll += __shfl_xor(ll, 32, 64);   // lane: l for q=l31 over this wave's kv set
  __syncthreads();                // all waves done reading K/V buffers

  float* Os = (float*)SMEM;                 // [qs 2][lane 64][33] padded
  float* Ls = (float*)SMEM + 2 * 64 * 33;   // [qs 2][lane 64]
  if (g == 1) {
    float* op = &Os[(qs * 64 + lane) * 33];
    #pragma unroll
    for (int r = 0; r < 16; ++r) { op[r] = O0[r]; op[16 + r] = O1[r]; }
    Ls[qs * 64 + lane] = ll;
  }
  __syncthreads();
  if (g == 0) {
    const float* op = &Os[(qs * 64 + lane) * 33];
    ll += Ls[qs * 64 + lane];
    #pragma unroll
    for (int r = 0; r < 16; ++r) { O0[r] += op[r]; O1[r] += op[16 + r]; }
    const float inv = 1.0f / ll;
    #pragma unroll
    for (int r = 0; r < 16; ++r) {
      const int crow = (r & 3) + 8 * (r >> 2) + 4 * hi;
      const float invr = __shfl(inv, crow, 64);
      const size_t o = qbase + (size_t)(q0 + qs * 32 + crow) * 1024 + h * 64;
      Ctx[o + l31]      = f2bf(O0[r] * invr);
      Ctx[o + 32 + l31] = f2bf(O1[r] * invr);
    }
  }
#undef STAGE
}

extern "C" void kernel_launch(void* const* d_in, const int* in_sizes, int n_in,
                              void* d_out, int out_size, void* d_ws, size_t ws_size,
                              hipStream_t stream) {
  const float* x  = (const float*)d_in[0];
  const float* Wq = (const float*)d_in[1];
  const float* Wk = (const float*)d_in[2];
  const float* Wv = (const float*)d_in[3];
  const float* Wo = (const float*)d_in[4];
  float* out = (float*)d_out;

  char* w = (char*)d_ws;
  short*  Xb    = (short*)w;   w += (size_t)MROWS * DM * 2;
  short*  WcatT = (short*)w;   w += (size_t)NQKV * DM * 2;
  short*  WoT   = (short*)w;   w += (size_t)DM * DM * 2;
  short*  Qbuf  = (short*)w;   w += (size_t)MROWS * DM * 2;
  short*  Kbuf  = (short*)w;   w += (size_t)MROWS * 256 * 2;
  short*  Vbuf  = (short*)w;   w += (size_t)MROWS * 256 * 2;
  short*  Vt    = (short*)w;   w += (size_t)8 * 64 * S_LEN * 2;
  short*  Ctx   = (short*)w;   w += (size_t)MROWS * DM * 2;
  float2* tab   = (float2*)w;  w += (size_t)S_LEN * 32 * 8;

  prep<<<dim3(4800), dim3(256), 0, stream>>>(x, Wq, Wk, Wv, Wo, Xb, WcatT, WoT, tab);

  // QKV GEMM with fused rope epilogue: grid 768 = 3 blocks/CU
  gemm_qkv<<<dim3(NQKV / 128, MROWS / 64), dim3(256), 0, stream>>>(Xb, WcatT, tab, Qbuf, Kbuf, Vbuf);
  transpose_v<<<dim3(32, 8), dim3(256), 0, stream>>>(Vbuf, Vt);
  fattn11<<<dim3(1024), dim3(256), 0, stream>>>(Qbuf, Kbuf, Vt, Ctx);
  gemm_bf16_t<64,128><<<dim3(DM / 128, MROWS / 64), dim3(256), 0, stream>>>(Ctx, WoT, out, MROWS, DM, DM);
}

// Round 6
// 164.221 us; speedup vs baseline: 1.2607x; 1.0019x over previous
//
#include <hip/hip_runtime.h>
#include <hip/hip_bf16.h>
#include <cstdint>
#include <math.h>

#define S_LEN 2048
#define DM 1024
#define NQKV 1536
#define MROWS 4096   // B * S
#define BKT 64

typedef __attribute__((ext_vector_type(8))) short short8;
typedef __attribute__((ext_vector_type(4))) float f32x4;
typedef __attribute__((ext_vector_type(16))) float f32x16;

// 0.125 (1/sqrt(64)) * log2(e), folded into Q at RoPE time
#define QFOLD 0.18033688011112042f

__device__ __forceinline__ short f2bf(float x) {
  union { float f; uint32_t u; } v; v.f = x;
  uint32_t r = (v.u + 0x7fffu + ((v.u >> 16) & 1u)) >> 16;
  return (short)(uint16_t)r;
}

__device__ __forceinline__ uint32_t pk2(float a, float b) {
  __hip_bfloat162 h = __float22bfloat162_rn(make_float2(a, b));
  union { __hip_bfloat162 h2; uint32_t u; } cv; cv.h2 = h;
  return cv.u;
}

// ---------------- merged prep: x->bf16 convert + 4 weight transposes + rope table ----------------
// blocks [0,4096): convert; [4096,4352): Wq; [4352,4416): Wk; [4416,4480): Wv;
// [4480,4736): Wo; [4736,4800): cos/sin table tab[s*32+j] (same cosf/sinf data
// path as the original rope kernel -> bit-identical rope values).
__global__ __launch_bounds__(256) void prep(const float* __restrict__ x,
    const float* __restrict__ Wq, const float* __restrict__ Wk,
    const float* __restrict__ Wv, const float* __restrict__ Wo,
    short* __restrict__ Xb, short* __restrict__ WcatT, short* __restrict__ WoT,
    float2* __restrict__ tab) {
  __shared__ short T[64 * 72];
  const int bb = blockIdx.x;
  const int tid = threadIdx.x;
  if (bb < 4096) {                       // fp32 -> bf16 vectorized convert
    const int i = bb * 256 + tid;        // exactly MROWS*DM/4 elements
    float4 v = ((const float4*)x)[i];
    short4 o;
    o.x = f2bf(v.x); o.y = f2bf(v.y); o.z = f2bf(v.z); o.w = f2bf(v.w);
    ((short4*)Xb)[i] = o;
    return;
  }
  if (bb >= 4736) {                      // rope cos/sin table: 2048 x 32 entries
    const int gid = (bb - 4736) * 256 + tid;   // [0,16384)
    #pragma unroll
    for (int e = 0; e < 4; ++e) {
      const int ii = gid + e * 16384;          // [0,65536)
      const int s = ii >> 5, j = ii & 31;
      const float inv = exp2f(-(float)j * 0.41524101186092029f);  // log2(10000)/32
      const float ang = (float)s * inv;
      tab[ii] = make_float2(cosf(ang), sinf(ang));
    }
    return;
  }
  const float* src; short* dst; int R, C, t2 = bb - 4096;
  if (t2 < 256)      { src = Wq; dst = WcatT;                        R = 1024; C = 1024; }
  else if (t2 < 320) { t2 -= 256; src = Wk; dst = WcatT + (size_t)1024*1024; R = 1024; C = 256; }
  else if (t2 < 384) { t2 -= 320; src = Wv; dst = WcatT + (size_t)1280*1024; R = 1024; C = 256; }
  else               { t2 -= 384; src = Wo; dst = WoT;               R = 1024; C = 1024; }
  const int r0 = (t2 & 15) * 64, c0 = (t2 >> 4) * 64;
  #pragma unroll
  for (int i = 0; i < 4; ++i) {
    int chunk = tid + i * 256;
    int r = chunk >> 4, cc = (chunk & 15) * 4;
    float4 v = *(const float4*)&src[(size_t)(r0 + r) * C + c0 + cc];
    T[(cc + 0) * 72 + r] = f2bf(v.x);
    T[(cc + 1) * 72 + r] = f2bf(v.y);
    T[(cc + 2) * 72 + r] = f2bf(v.z);
    T[(cc + 3) * 72 + r] = f2bf(v.w);
  }
  __syncthreads();
  #pragma unroll
  for (int i = 0; i < 2; ++i) {
    int chunk = tid + i * 256;
    int rr = chunk >> 3, kk = (chunk & 7) * 8;
    *(uint4*)&dst[(size_t)(c0 + rr) * R + r0 + kk] = *(uint4*)&T[rr * 72 + kk];
  }
}

// ---------------- bf16 MFMA GEMM, m97-style staging, tile-templated (plain fp32 C) ----------------
template<int BMT, int BNT>
__global__ __launch_bounds__(256) void gemm_bf16_t(const short* __restrict__ A,
    const short* __restrict__ BT, float* __restrict__ C, int M, int N, int K) {
  constexpr int MI = BMT / 32, NI = BNT / 32;
  __shared__ short As[BMT * BKT];
  __shared__ short Bs[BNT * BKT];
  const int tid = threadIdx.x;
  const int wave = tid >> 6, lane = tid & 63;
  const int quad = lane >> 4, l15 = lane & 15;
  const int wm = (wave >> 1) * (BMT / 2), wn = (wave & 1) * (BNT / 2);
  const int m0 = blockIdx.y * BMT, n0 = blockIdx.x * BNT;
  const int rA = wave * (BMT / 4) + (lane >> 3);
  const int rB = wave * (BNT / 4) + (lane >> 3);
  const int scol = (lane & 7) * 8;

  f32x4 acc[MI][NI] = {};

  for (int k0 = 0; k0 < K; k0 += BKT) {
    __syncthreads();
    #pragma unroll
    for (int j = 0; j < MI; ++j)
      __builtin_amdgcn_global_load_lds(
          (const __attribute__((address_space(1))) void*)&A[(size_t)(m0 + rA + j * 8) * K + k0 + scol],
          (__attribute__((address_space(3))) void*)&As[(wave * MI + j) * 512],
          16, 0, 0);
    #pragma unroll
    for (int j = 0; j < NI; ++j)
      __builtin_amdgcn_global_load_lds(
          (const __attribute__((address_space(1))) void*)&BT[(size_t)(n0 + rB + j * 8) * K + k0 + scol],
          (__attribute__((address_space(3))) void*)&Bs[(wave * NI + j) * 512],
          16, 0, 0);
    __syncthreads();
    #pragma unroll
    for (int ks = 0; ks < 2; ++ks) {
      short8 af[MI], bfr[NI];
      #pragma unroll
      for (int mi = 0; mi < MI; ++mi)
        af[mi] = *(const short8*)&As[(wm + mi*16 + l15)*BKT + ks*32 + quad*8];
      #pragma unroll
      for (int ni = 0; ni < NI; ++ni)
        bfr[ni] = *(const short8*)&Bs[(wn + ni*16 + l15)*BKT + ks*32 + quad*8];
      #pragma unroll
      for (int mi = 0; mi < MI; ++mi)
        #pragma unroll
        for (int ni = 0; ni < NI; ++ni)
          acc[mi][ni] = __builtin_amdgcn_mfma_f32_16x16x32_bf16(af[mi], bfr[ni], acc[mi][ni], 0, 0, 0);
    }
  }
  #pragma unroll
  for (int mi = 0; mi < MI; ++mi)
    #pragma unroll
    for (int ni = 0; ni < NI; ++ni)
      #pragma unroll
      for (int r = 0; r < 4; ++r)
        C[(size_t)(m0 + wm + mi*16 + quad*4 + r)*N + (n0 + wn + ni*16 + l15)] = acc[mi][ni][r];
}

// ---------------- QKV GEMM with fused RoPE + fused V-transpose epilogue ----------------
// 64x128 tile. Q blocks: rope*QFOLD. K blocks: rope + XOR-swizzle. V blocks:
// transpose in (dead) staging LDS and write Vt[(b*4+kvh)*64+d][s] directly,
// XOR-swizzled s^((d&7)<<3) within 64-s chunks — replaces the transpose_v kernel.
__global__ __launch_bounds__(256, 3) void gemm_qkv(const short* __restrict__ A,
    const short* __restrict__ BT, const float2* __restrict__ tab,
    short* __restrict__ Qb, short* __restrict__ Kb, short* __restrict__ Vt) {
  constexpr int MI = 2, NI = 4;   // 64 x 128
  __shared__ short SM[12288];     // As[64*64] @0, Bs[128*64] @4096; V-transpose T[128][80] aliases
  short* As = SM;
  short* Bs = SM + 4096;
  const int tid = threadIdx.x;
  const int wave = tid >> 6, lane = tid & 63;
  const int quad = lane >> 4, l15 = lane & 15;
  const int wm = (wave >> 1) * 32, wn = (wave & 1) * 64;
  const int m0 = blockIdx.y * 64, n0 = blockIdx.x * 128;
  const int rA = wave * 16 + (lane >> 3);
  const int rB = wave * 32 + (lane >> 3);
  const int scol = (lane & 7) * 8;

  f32x4 acc[MI][NI] = {};

  for (int k0 = 0; k0 < DM; k0 += BKT) {
    __syncthreads();
    #pragma unroll
    for (int j = 0; j < MI; ++j)
      __builtin_amdgcn_global_load_lds(
          (const __attribute__((address_space(1))) void*)&A[(size_t)(m0 + rA + j * 8) * DM + k0 + scol],
          (__attribute__((address_space(3))) void*)&As[(wave * MI + j) * 512],
          16, 0, 0);
    #pragma unroll
    for (int j = 0; j < NI; ++j)
      __builtin_amdgcn_global_load_lds(
          (const __attribute__((address_space(1))) void*)&BT[(size_t)(n0 + rB + j * 8) * DM + k0 + scol],
          (__attribute__((address_space(3))) void*)&Bs[(wave * NI + j) * 512],
          16, 0, 0);
    __syncthreads();
    #pragma unroll
    for (int ks = 0; ks < 2; ++ks) {
      short8 af[MI], bfr[NI];
      #pragma unroll
      for (int mi = 0; mi < MI; ++mi)
        af[mi] = *(const short8*)&As[(wm + mi*16 + l15)*BKT + ks*32 + quad*8];
      #pragma unroll
      for (int ni = 0; ni < NI; ++ni)
        bfr[ni] = *(const short8*)&Bs[(wn + ni*16 + l15)*BKT + ks*32 + quad*8];
      #pragma unroll
      for (int mi = 0; mi < MI; ++mi)
        #pragma unroll
        for (int ni = 0; ni < NI; ++ni)
          acc[mi][ni] = __builtin_amdgcn_mfma_f32_16x16x32_bf16(af[mi], bfr[ni], acc[mi][ni], 0, 0, 0);
    }
  }

  const int c0 = n0 + wn;                 // multiple of 64
  if (n0 < 1024) {                        // ---- Q: rope * QFOLD ----
    #pragma unroll
    for (int mi = 0; mi < MI; ++mi)
      #pragma unroll
      for (int r = 0; r < 4; ++r) {
        const int row = m0 + wm + mi*16 + quad*4 + r;
        const int s = row & (S_LEN - 1);
        #pragma unroll
        for (int ni = 0; ni < 2; ++ni) {
          const int j = ni*16 + l15;
          const float2 cn = tab[s*32 + j];
          const float x1 = acc[mi][ni][r], x2 = acc[mi][ni+2][r];
          Qb[(size_t)row*1024 + c0 + j]      = f2bf((x1*cn.x - x2*cn.y) * QFOLD);
          Qb[(size_t)row*1024 + c0 + j + 32] = f2bf((x2*cn.x + x1*cn.y) * QFOLD);
        }
      }
  } else if (n0 < 1280) {                 // ---- K: rope + XOR-swizzle ----
    const int hh = (c0 - 1024) >> 6;
    #pragma unroll
    for (int mi = 0; mi < MI; ++mi)
      #pragma unroll
      for (int r = 0; r < 4; ++r) {
        const int row = m0 + wm + mi*16 + quad*4 + r;
        const int s = row & (S_LEN - 1);
        const int sw = (s & 7) << 3;
        #pragma unroll
        for (int ni = 0; ni < 2; ++ni) {
          const int j = ni*16 + l15;
          const float2 cn = tab[s*32 + j];
          const float x1 = acc[mi][ni][r], x2 = acc[mi][ni+2][r];
          Kb[(size_t)row*256 + hh*64 + (j ^ sw)]        = f2bf(x1*cn.x - x2*cn.y);
          Kb[(size_t)row*256 + hh*64 + ((j + 32) ^ sw)] = f2bf(x2*cn.x + x1*cn.y);
        }
      }
  } else {                                // ---- V: LDS transpose -> Vt (swizzled) ----
    __syncthreads();                      // staging LDS dead; reuse as T[128 vcol][80]
    #pragma unroll
    for (int mi = 0; mi < MI; ++mi)
      #pragma unroll
      for (int ni = 0; ni < NI; ++ni) {
        short4 p;
        p.x = f2bf(acc[mi][ni][0]); p.y = f2bf(acc[mi][ni][1]);
        p.z = f2bf(acc[mi][ni][2]); p.w = f2bf(acc[mi][ni][3]);
        *(short4*)&SM[(wn + ni*16 + l15)*80 + wm + mi*16 + quad*4] = p;
      }
    __syncthreads();
    const int b_ = m0 >> 11, sbase = m0 & (S_LEN - 1);
    #pragma unroll
    for (int i = 0; i < 4; ++i) {
      const int chunk = tid + i * 256;      // [0,1024)
      const int vl = chunk >> 3;            // local vcol 0..127
      const int kk = (chunk & 7) * 8;       // 0..56
      const int vcol = (n0 - 1280) + vl;
      const int kvh = vcol >> 6, dd = vcol & 63;
      uint4 v = *(uint4*)&SM[vl*80 + kk];
      *(uint4*)&Vt[((size_t)((b_*4 + kvh)*64 + dd))*S_LEN + sbase + (kk ^ ((dd & 7) << 3))] = v;
    }
  }
}

// ---------------- causal GQA flash attention v12: ring-3 + split dependency chains ----------------
// grid 1024 = (h:16, b:2, jt:32 longest-first). Block = 256 threads = 4 waves:
//   qs = wav&1 -> q-subtile of 32; g = wav>>1 -> kv half (32 rows) of a 64-kv unit.
// LDS = 3 x 16KB ring (48KB) -> 3 blocks/CU = 12 waves/CU (3/SIMD). Counted
// vmcnt keeps the next unit's loads in flight across the barrier. v12: QK^T
// split into two independent 2-MFMA chains (+vector add); PV split into
// per-s2 accumulators (O/P) summed once at the end — halves intra-unit
// dependency depth for single-wave latency hiding.
__global__ __launch_bounds__(256, 3) void fattn12(const short* __restrict__ Qb,
    const short* __restrict__ Kb, const short* __restrict__ Vt, short* __restrict__ Ctx) {
  __shared__ short SMEM[24576];   // 3 bufs x (K[64][64] @ +0, VT[64][64] @ +4096 shorts)
  const int idx = blockIdx.x;
  const int h   = idx & 15;
  const int b   = (idx >> 4) & 1;
  const int jt  = 31 - (idx >> 5);         // longest-first dispatch
  const int kvh = h >> 2;
  const int tid = threadIdx.x, wav = tid >> 6, lane = tid & 63;
  const int l31 = lane & 31, hi = lane >> 5;
  const int qs = wav & 1, g = wav >> 1;    // g in {0,1}
  const int sx = (l31 & 7) << 3;           // XOR-swizzle key (matches producers)
  const size_t qbase  = (size_t)b * S_LEN * 1024;
  const size_t kbase  = (size_t)b * S_LEN * 256;
  const size_t vtbase = (size_t)(b * 4 + kvh) * 64 * S_LEN;

  const short* kptr = Kb + kbase + (size_t)(wav * 16 + (lane >> 3)) * 256 + kvh * 64 + (lane & 7) * 8;
  const short* vptr = Vt + vtbase + (size_t)(wav * 16 + (lane >> 3)) * 2048 + (lane & 7) * 8;

#define STAGE(u) do { \
    const int bi_ = (u) % 3; \
    const short* kp_ = kptr + (size_t)(u) * 16384; \
    const short* vp_ = vptr + (u) * 64; \
    short* kd_ = &SMEM[bi_ * 8192 + wav * 1024]; \
    short* vd_ = &SMEM[bi_ * 8192 + 4096 + wav * 1024]; \
    _Pragma("unroll") \
    for (int i_ = 0; i_ < 2; ++i_) { \
      __builtin_amdgcn_global_load_lds((const __attribute__((address_space(1))) void*)(kp_ + i_ * 2048), \
          (__attribute__((address_space(3))) void*)(kd_ + i_ * 512), 16, 0, 0); \
      __builtin_amdgcn_global_load_lds((const __attribute__((address_space(1))) void*)(vp_ + i_ * 16384), \
          (__attribute__((address_space(3))) void*)(vd_ + i_ * 512), 16, 0, 0); \
    } \
  } while (0)

  const int q0 = jt * 64;
  const int ntiles = jt + 1;            // 64-kv units
  const int qg = q0 + qs * 32 + l31;    // this lane's q column

  // Q B-frags: lane holds Q[q=l31 of subtile][d = ks*16 + hi*8 + j]
  short8 qf[4];
  {
    const short* qp = &Qb[qbase + (size_t)qg * 1024 + h * 64 + hi * 8];
    #pragma unroll
    for (int ks = 0; ks < 4; ++ks) qf[ks] = *(const short8*)(qp + ks * 16);
  }

  f32x16 O0 = {}, O1 = {};   // PV accumulators, s2 = 0
  f32x16 P0 = {}, P1 = {};   // PV accumulators, s2 = 1 (independent chains)
  float la0 = 0.f, la1 = 0.f, la2 = 0.f, la3 = 0.f;

  STAGE(0);
  if (ntiles > 1) STAGE(1);

  for (int t = 0; t < ntiles; ++t) {
    const int k0 = t * 64;
    const int rem = ntiles - 1 - t;
    if (rem >= 1) { asm volatile("s_waitcnt vmcnt(4)" ::: "memory"); }
    else          { asm volatile("s_waitcnt vmcnt(0)" ::: "memory"); }
    __builtin_amdgcn_sched_barrier(0);
    __builtin_amdgcn_s_barrier();
    if (t + 2 < ntiles) STAGE(t + 2);   // writes buf (t+2)%3 == (t-1)%3: reads done

    const short* ks_ = &SMEM[(t % 3) * 8192];
    const short* vs_ = &SMEM[(t % 3) * 8192 + 4096];

    // St = K Q^T over this wave's 32-kv half: two independent 2-MFMA chains
    f32x16 sc;
    __builtin_amdgcn_s_setprio(1);
    {
      const int r = g * 32 + l31;
      short8 kf0 = *(const short8*)&ks_[r * 64 + ((0 * 16 + hi * 8) ^ sx)];
      short8 kf1 = *(const short8*)&ks_[r * 64 + ((1 * 16 + hi * 8) ^ sx)];
      short8 kf2 = *(const short8*)&ks_[r * 64 + ((2 * 16 + hi * 8) ^ sx)];
      short8 kf3 = *(const short8*)&ks_[r * 64 + ((3 * 16 + hi * 8) ^ sx)];
      f32x16 a0 = {}, a1 = {};
      a0 = __builtin_amdgcn_mfma_f32_32x32x16_bf16(kf0, qf[0], a0, 0, 0, 0);
      a1 = __builtin_amdgcn_mfma_f32_32x32x16_bf16(kf2, qf[2], a1, 0, 0, 0);
      a0 = __builtin_amdgcn_mfma_f32_32x32x16_bf16(kf1, qf[1], a0, 0, 0, 0);
      a1 = __builtin_amdgcn_mfma_f32_32x32x16_bf16(kf3, qf[3], a1, 0, 0, 0);
      #pragma unroll
      for (int r2 = 0; r2 < 16; ++r2) sc[r2] = a0[r2] + a1[r2];
    }
    __builtin_amdgcn_s_setprio(0);

    if (t == ntiles - 1) {
      #pragma unroll
      for (int r = 0; r < 16; ++r) {
        const int kvg = k0 + g * 32 + (r & 3) + 8 * (r >> 2) + 4 * hi;
        if (kvg > qg) sc[r] = -1e30f;
      }
    }

    // no-max softmax: p = exp2(s); PV A-frags in-register (T12)
    short8 af[2];
    {
      #pragma unroll
      for (int r = 0; r < 16; ++r) sc[r] = exp2f(sc[r]);
      la0 += (sc[0] + sc[1]) + (sc[2] + sc[3]);
      la1 += (sc[4] + sc[5]) + (sc[6] + sc[7]);
      la2 += (sc[8] + sc[9]) + (sc[10] + sc[11]);
      la3 += (sc[12] + sc[13]) + (sc[14] + sc[15]);
      #pragma unroll
      for (int st = 0; st < 2; ++st) {
        uint32_t x0 = pk2(sc[st * 8 + 0], sc[st * 8 + 1]);
        uint32_t x1 = pk2(sc[st * 8 + 2], sc[st * 8 + 3]);
        uint32_t x2 = pk2(sc[st * 8 + 4], sc[st * 8 + 5]);
        uint32_t x3 = pk2(sc[st * 8 + 6], sc[st * 8 + 7]);
        asm("v_permlane32_swap_b32 %0, %1" : "+v"(x0), "+v"(x2));
        asm("v_permlane32_swap_b32 %0, %1" : "+v"(x1), "+v"(x3));
        union { short8 s8; uint32_t u[4]; } cv;
        cv.u[0] = x0; cv.u[1] = x1; cv.u[2] = x2; cv.u[3] = x3;
        af[st] = cv.s8;
      }
    }

    // O += P V over the 32-kv half: 4 independent accumulator chains (O0,O1,P0,P1)
    __builtin_amdgcn_s_setprio(1);
    {
      const int co0 = g * 32 + hi * 8;
      const int co1 = g * 32 + 16 + hi * 8;
      short8 bv00 = *(const short8*)&vs_[l31 * 64 + (co0 ^ sx)];
      short8 bv01 = *(const short8*)&vs_[(32 + l31) * 64 + (co0 ^ sx)];
      short8 bv10 = *(const short8*)&vs_[l31 * 64 + (co1 ^ sx)];
      short8 bv11 = *(const short8*)&vs_[(32 + l31) * 64 + (co1 ^ sx)];
      O0 = __builtin_amdgcn_mfma_f32_32x32x16_bf16(af[0], bv00, O0, 0, 0, 0);
      O1 = __builtin_amdgcn_mfma_f32_32x32x16_bf16(af[0], bv01, O1, 0, 0, 0);
      P0 = __builtin_amdgcn_mfma_f32_32x32x16_bf16(af[1], bv10, P0, 0, 0, 0);
      P1 = __builtin_amdgcn_mfma_f32_32x32x16_bf16(af[1], bv11, P1, 0, 0, 0);
    }
    __builtin_amdgcn_s_setprio(0);
  }

  // fold the split PV accumulators
  #pragma unroll
  for (int r = 0; r < 16; ++r) { O0[r] += P0[r]; O1[r] += P1[r]; }

  // ---- combine the two kv halves (linear: no-max softmax, no rescale) ----
  float ll = (la0 + la1) + (la2 + la3);
  ll += __shfl_xor(ll, 32, 64);   // lane: l for q=l31 over this wave's kv set
  __syncthreads();                // all waves done reading K/V buffers

  float* Os = (float*)SMEM;                 // [qs 2][lane 64][33] padded
  float* Ls = (float*)SMEM + 2 * 64 * 33;   // [qs 2][lane 64]
  if (g == 1) {
    float* op = &Os[(qs * 64 + lane) * 33];
    #pragma unroll
    for (int r = 0; r < 16; ++r) { op[r] = O0[r]; op[16 + r] = O1[r]; }
    Ls[qs * 64 + lane] = ll;
  }
  __syncthreads();
  if (g == 0) {
    const float* op = &Os[(qs * 64 + lane) * 33];
    ll += Ls[qs * 64 + lane];
    #pragma unroll
    for (int r = 0; r < 16; ++r) { O0[r] += op[r]; O1[r] += op[16 + r]; }
    const float inv = 1.0f / ll;
    #pragma unroll
    for (int r = 0; r < 16; ++r) {
      const int crow = (r & 3) + 8 * (r >> 2) + 4 * hi;
      const float invr = __shfl(inv, crow, 64);
      const size_t o = qbase + (size_t)(q0 + qs * 32 + crow) * 1024 + h * 64;
      Ctx[o + l31]      = f2bf(O0[r] * invr);
      Ctx[o + 32 + l31] = f2bf(O1[r] * invr);
    }
  }
#undef STAGE
}

extern "C" void kernel_launch(void* const* d_in, const int* in_sizes, int n_in,
                              void* d_out, int out_size, void* d_ws, size_t ws_size,
                              hipStream_t stream) {
  const float* x  = (const float*)d_in[0];
  const float* Wq = (const float*)d_in[1];
  const float* Wk = (const float*)d_in[2];
  const float* Wv = (const float*)d_in[3];
  const float* Wo = (const float*)d_in[4];
  float* out = (float*)d_out;

  char* w = (char*)d_ws;
  short*  Xb    = (short*)w;   w += (size_t)MROWS * DM * 2;
  short*  WcatT = (short*)w;   w += (size_t)NQKV * DM * 2;
  short*  WoT   = (short*)w;   w += (size_t)DM * DM * 2;
  short*  Qbuf  = (short*)w;   w += (size_t)MROWS * DM * 2;
  short*  Kbuf  = (short*)w;   w += (size_t)MROWS * 256 * 2;
  short*  Vt    = (short*)w;   w += (size_t)8 * 64 * S_LEN * 2;
  short*  Ctx   = (short*)w;   w += (size_t)MROWS * DM * 2;
  float2* tab   = (float2*)w;  w += (size_t)S_LEN * 32 * 8;

  prep<<<dim3(4800), dim3(256), 0, stream>>>(x, Wq, Wk, Wv, Wo, Xb, WcatT, WoT, tab);

  // QKV GEMM with fused rope + fused V-transpose epilogue
  gemm_qkv<<<dim3(NQKV / 128, MROWS / 64), dim3(256), 0, stream>>>(Xb, WcatT, tab, Qbuf, Kbuf, Vt);
  fattn12<<<dim3(1024), dim3(256), 0, stream>>>(Qbuf, Kbuf, Vt, Ctx);
  gemm_bf16_t<64,128><<<dim3(DM / 128, MROWS / 64), dim3(256), 0, stream>>>(Ctx, WoT, out, MROWS, DM, DM);
}